// Round 13
// baseline (531.423 us; speedup 1.0000x reference)
//
#include <hip/hip_runtime.h>
#include <hip/hip_fp16.h>
#include <math.h>

#define BLK 256
#define CBSH 9           // 512 nodes per coarse bucket (196 buckets for n=100k)
#define CBN 512
#define NCBC 256
#define NB2 512

__device__ __forceinline__ float selu_f(float x) {
    const float kScale = 1.0507009873554805f;
    const float kAlpha = 1.6732632423543772f;
    return x > 0.0f ? kScale * x : kScale * kAlpha * expm1f(x);
}

__device__ __forceinline__ float2 h2f2(unsigned u) {
    __half2 h = *reinterpret_cast<__half2*>(&u);
    return __half22float2(h);
}
__device__ __forceinline__ void h8_set(float* a, uint4 v) {
    float2 f0 = h2f2(v.x), f1 = h2f2(v.y), f2 = h2f2(v.z), f3 = h2f2(v.w);
    a[0] = f0.x; a[1] = f0.y; a[2] = f1.x; a[3] = f1.y;
    a[4] = f2.x; a[5] = f2.y; a[6] = f3.x; a[7] = f3.y;
}
__device__ __forceinline__ void h8_add(float* a, uint4 v) {
    float2 f0 = h2f2(v.x), f1 = h2f2(v.y), f2 = h2f2(v.z), f3 = h2f2(v.w);
    a[0] += f0.x; a[1] += f0.y; a[2] += f1.x; a[3] += f1.y;
    a[4] += f2.x; a[5] += f2.y; a[6] += f3.x; a[7] += f3.y;
}
__device__ __forceinline__ uint4 f8_pack(const float* a) {
    __half2 h0 = __float22half2_rn(make_float2(a[0], a[1]));
    __half2 h1 = __float22half2_rn(make_float2(a[2], a[3]));
    __half2 h2 = __float22half2_rn(make_float2(a[4], a[5]));
    __half2 h3 = __float22half2_rn(make_float2(a[6], a[7]));
    uint4 u;
    u.x = *reinterpret_cast<unsigned*>(&h0);
    u.y = *reinterpret_cast<unsigned*>(&h1);
    u.z = *reinterpret_cast<unsigned*>(&h2);
    u.w = *reinterpret_cast<unsigned*>(&h3);
    return u;
}

// ---------------- CSR build (two-pass counting sort; identical to rounds 10/12) ----------------
__global__ void k_cnt(const int* __restrict__ dst, int* __restrict__ H, int e, int nbkt) {
    __shared__ int hist[NCBC];
    int tid = threadIdx.x;
    for (int b = tid; b < nbkt; b += BLK) hist[b] = 0;
    __syncthreads();
    int per = (e + NB2 - 1) / NB2;
    int lo = blockIdx.x * per;
    int hi = min(e, lo + per);
    for (int i = lo + tid; i < hi; i += BLK) atomicAdd(&hist[dst[i] >> CBSH], 1);
    __syncthreads();
    for (int b = tid; b < nbkt; b += BLK) H[blockIdx.x * nbkt + b] = hist[b];
}

__global__ void k_bsum(const int* __restrict__ H, int* __restrict__ bstart, int nbkt, int e) {
    __shared__ int tot[NCBC];
    int tid = threadIdx.x;
    for (int b = tid; b < nbkt; b += BLK) {
        int s = 0;
        for (int i = 0; i < NB2; ++i) s += H[i * nbkt + b];
        tot[b] = s;
    }
    __syncthreads();
    if (tid == 0) {
        int acc = 0;
        for (int b = 0; b < nbkt; ++b) {
            bstart[b] = acc;
            acc += tot[b];
        }
        bstart[nbkt] = acc;
    }
}

__global__ void k_off(int* __restrict__ H, const int* __restrict__ bstart, int nbkt) {
    __shared__ int lds[BLK];
    int b = blockIdx.x, tid = threadIdx.x;
    int v0 = H[(2 * tid) * nbkt + b];
    int v1 = H[(2 * tid + 1) * nbkt + b];
    int pair = v0 + v1;
    lds[tid] = pair;
    __syncthreads();
    int val = pair;
    for (int off = 1; off < BLK; off <<= 1) {
        int t2 = (tid >= off) ? lds[tid - off] : 0;
        __syncthreads();
        val += t2;
        lds[tid] = val;
        __syncthreads();
    }
    int excl = val - pair + bstart[b];
    H[(2 * tid) * nbkt + b] = excl;
    H[(2 * tid + 1) * nbkt + b] = excl + v0;
}

__global__ void k_scatter2(const int* __restrict__ src, const int* __restrict__ dst,
                           const int* __restrict__ H, unsigned* __restrict__ slab,
                           int e, int nbkt) {
    __shared__ int cur[NCBC];
    int tid = threadIdx.x;
    for (int b = tid; b < nbkt; b += BLK) cur[b] = H[blockIdx.x * nbkt + b];
    __syncthreads();
    int per = (e + NB2 - 1) / NB2;
    int lo = blockIdx.x * per;
    int hi = min(e, lo + per);
    for (int i = lo + tid; i < hi; i += BLK) {
        int s = src[i], d = dst[i];
        int b = d >> CBSH;
        int pos = atomicAdd(&cur[b], 1);
        slab[pos] = ((unsigned)s << CBSH) | (unsigned)(d & (CBN - 1));
    }
}

__global__ void k_build(const int* __restrict__ bstart, const unsigned* __restrict__ slab,
                        int* __restrict__ rowptr, float* __restrict__ dinv,
                        int* __restrict__ csr, int n, int e) {
    __shared__ int hist[CBN];
    __shared__ int stmp[BLK];
    int b = blockIdx.x, tid = threadIdx.x;
    hist[2 * tid] = 0;
    hist[2 * tid + 1] = 0;
    __syncthreads();
    int lo = bstart[b], hi = bstart[b + 1];
    for (int i = lo + tid; i < hi; i += BLK) atomicAdd(&hist[slab[i] & (CBN - 1)], 1);
    __syncthreads();
    int h0 = hist[2 * tid], h1 = hist[2 * tid + 1];
    int pair = h0 + h1;
    stmp[tid] = pair;
    __syncthreads();
    int val = pair;
    for (int off = 1; off < BLK; off <<= 1) {
        int t2 = (tid >= off) ? stmp[tid - off] : 0;
        __syncthreads();
        val += t2;
        stmp[tid] = val;
        __syncthreads();
    }
    int e0 = lo + val - pair;
    int e1 = e0 + h0;
    hist[2 * tid] = e0;
    hist[2 * tid + 1] = e1;
    int node0 = b << CBSH;
    int nA = node0 + 2 * tid, nB = nA + 1;
    if (nA < n) { rowptr[nA] = e0; dinv[nA] = rsqrtf((float)(h0 + 1)); }
    if (nB < n) { rowptr[nB] = e1; dinv[nB] = rsqrtf((float)(h1 + 1)); }
    if (b == 0 && tid == 0) rowptr[n] = e;
    __syncthreads();
    for (int i = lo + tid; i < hi; i += BLK) {
        unsigned p = slab[i];
        int pos = atomicAdd(&hist[p & (CBN - 1)], 1);
        csr[pos] = (int)(p >> CBSH);
    }
}

// ---------------- layer compute ----------------
// G: fp16 chunk-SoA [chunk][N] uint4.  A: fp32 chunk-SoA [chunk][N] float4-pairs.

__global__ void k_gemm1(const float* __restrict__ x, const float* __restrict__ W,
                        const float* __restrict__ dinv, uint4* __restrict__ G, int n) {
    int i = blockIdx.x * BLK + threadIdx.x;
    if (i >= n) return;
    const float4* xr = reinterpret_cast<const float4*>(x + (size_t)i * 128);
    float acc[16];
#pragma unroll
    for (int f = 0; f < 16; ++f) acc[f] = 0.0f;
#pragma unroll
    for (int k4 = 0; k4 < 32; ++k4) {
        float4 xv = xr[k4];
        float xs[4] = {xv.x, xv.y, xv.z, xv.w};
#pragma unroll
        for (int j = 0; j < 4; ++j) {
            int k = k4 * 4 + j;
#pragma unroll
            for (int f = 0; f < 15; ++f) acc[f] = fmaf(xs[j], W[k * 15 + f], acc[f]);
        }
    }
    float di = dinv[i];
#pragma unroll
    for (int f = 0; f < 15; ++f) acc[f] *= di;
    acc[15] = 0.0f;
    G[i] = f8_pack(acc);
    G[(size_t)n + i] = f8_pack(acc + 8);
}

// layer-1 agg (output-space, chunk-sharded) + fused G2 epilogue.
__global__ void k_aggF(const int* __restrict__ rowptr, const int* __restrict__ csr,
                       const uint4* __restrict__ hs, uint4* __restrict__ G2,
                       const float* __restrict__ dinv, const float* __restrict__ bias, int n) {
    int chunk = blockIdx.x & 1;
    int d = (blockIdx.x >> 1) * BLK + threadIdx.x;
    if (d >= n) return;
    const uint4* gs = hs + (size_t)chunk * n;
    float a0[8], a1[8] = {0};
    h8_set(a0, gs[d]);
    int p = rowptr[d], end = rowptr[d + 1];
    for (; p + 4 <= end; p += 4) {
        int r0 = csr[p], r1 = csr[p + 1], r2 = csr[p + 2], r3 = csr[p + 3];
        uint4 v0 = gs[r0], v1 = gs[r1], v2 = gs[r2], v3 = gs[r3];
        h8_add(a0, v0); h8_add(a1, v1); h8_add(a0, v2); h8_add(a1, v3);
    }
    for (; p < end; ++p) h8_add(a0, gs[csr[p]]);
    float di = dinv[d];
    float g[8];
    int colb = chunk * 8;
#pragma unroll
    for (int j = 0; j < 8; ++j) {
        int col = colb + j;
        float s = a0[j] + a1[j];
        g[j] = (col < 15) ? di * selu_f(di * s + bias[col]) : 0.0f;
    }
    G2[(size_t)chunk * n + d] = f8_pack(g);
}

// input-space agg: one chunk per block-class -> XCD-private table slice.
template <int CHM, int FCH>
__global__ void k_aggK(const int* __restrict__ rowptr, const int* __restrict__ csr,
                       const uint4* __restrict__ G, float4* __restrict__ A, int n) {
    int chunk = blockIdx.x & (CHM - 1);
    int d = (blockIdx.x / CHM) * BLK + threadIdx.x;
    if (d >= n) return;
    if (FCH < CHM && chunk >= FCH) return;
    const uint4* gs = G + (size_t)chunk * n;
    float a0[8], a1[8] = {0};
    h8_set(a0, gs[d]);
    int p = rowptr[d], end = rowptr[d + 1];
    for (; p + 4 <= end; p += 4) {
        int r0 = csr[p], r1 = csr[p + 1], r2 = csr[p + 2], r3 = csr[p + 3];
        uint4 v0 = gs[r0], v1 = gs[r1], v2 = gs[r2], v3 = gs[r3];
        h8_add(a0, v0); h8_add(a1, v1); h8_add(a0, v2); h8_add(a1, v3);
    }
    for (; p < end; ++p) h8_add(a0, gs[csr[p]]);
    size_t o = ((size_t)chunk * n + d) * 2;
    A[o] = make_float4(a0[0] + a1[0], a0[1] + a1[1], a0[2] + a1[2], a0[3] + a1[3]);
    A[o + 1] = make_float4(a0[4] + a1[4], a0[5] + a1[5], a0[6] + a1[6], a0[7] + a1[7]);
}

// Split mid-gemm: FCH waves per 64-node group; wave `part` computes output chunk `part`
// (cols [8*part, 8*part+8)) with acc[8]. W loads wave-uniform; A rows L1-shared.
// Per-output accumulation order identical to the monolithic version.
template <int KCH, int K, int F, int FCH>
__global__ void k_gemmS(const float4* __restrict__ A4, const float* __restrict__ W,
                        const float* __restrict__ bias, const float* __restrict__ dinv,
                        uint4* __restrict__ G, int n) {
    int lane = threadIdx.x & 63;
    int part = threadIdx.x >> 6;   // 0..FCH-1
    int i = blockIdx.x * 64 + lane;
    if (i >= n) return;
    float acc[8];
#pragma unroll
    for (int f = 0; f < 8; ++f) acc[f] = 0.0f;
#pragma unroll
    for (int c = 0; c < KCH; ++c) {
        size_t o = ((size_t)c * n + i) * 2;
        float4 lo = A4[o], hi = A4[o + 1];
        float xs[8] = {lo.x, lo.y, lo.z, lo.w, hi.x, hi.y, hi.z, hi.w};
#pragma unroll
        for (int j = 0; j < 8; ++j) {
            int k = c * 8 + j;
            if (k < K) {
#pragma unroll
                for (int f = 0; f < 8; ++f) {
                    int col = part * 8 + f;
                    if (col < F) acc[f] = fmaf(xs[j], W[k * F + col], acc[f]);
                }
            }
        }
    }
    float di = dinv[i];
    float g[8];
#pragma unroll
    for (int f = 0; f < 8; ++f) {
        int col = part * 8 + f;
        g[f] = (col < F) ? di * selu_f(di * acc[f] + bias[col]) : 0.0f;
    }
    G[(size_t)part * n + i] = f8_pack(g);
}

// Split final gemm: 3 waves per 64-node group; wave `part` computes cols [12*part, 12*part+12).
__global__ void k_gemm4S(const float4* __restrict__ A4, const float* __restrict__ W,
                         const float* __restrict__ bias, const float* __restrict__ dinv,
                         float* __restrict__ out, int n) {
    int lane = threadIdx.x & 63;
    int part = threadIdx.x >> 6;   // 0..2
    int i = blockIdx.x * 64 + lane;
    if (i >= n) return;
    float acc[12];
#pragma unroll
    for (int f = 0; f < 12; ++f) acc[f] = 0.0f;
#pragma unroll
    for (int c = 0; c < 4; ++c) {
        size_t o = ((size_t)c * n + i) * 2;
        float4 lo = A4[o], hi = A4[o + 1];
        float xs[8] = {lo.x, lo.y, lo.z, lo.w, hi.x, hi.y, hi.z, hi.w};
#pragma unroll
        for (int j = 0; j < 8; ++j) {
            int k = c * 8 + j;
            if (k < 27) {
#pragma unroll
                for (int f = 0; f < 12; ++f)
                    acc[f] = fmaf(xs[j], W[k * 36 + part * 12 + f], acc[f]);
            }
        }
    }
    float di = dinv[i];
    float* op = out + (size_t)i * 36 + part * 12;
#pragma unroll
    for (int f4 = 0; f4 < 3; ++f4) {
        float4 r;
        r.x = selu_f(di * acc[f4 * 4 + 0] + bias[part * 12 + f4 * 4 + 0]);
        r.y = selu_f(di * acc[f4 * 4 + 1] + bias[part * 12 + f4 * 4 + 1]);
        r.z = selu_f(di * acc[f4 * 4 + 2] + bias[part * 12 + f4 * 4 + 2]);
        r.w = selu_f(di * acc[f4 * 4 + 3] + bias[part * 12 + f4 * 4 + 3]);
        *reinterpret_cast<float4*>(op + f4 * 4) = r;
    }
}

extern "C" void kernel_launch(void* const* d_in, const int* in_sizes, int n_in,
                              void* d_out, int out_size, void* d_ws, size_t ws_size,
                              hipStream_t stream) {
    const float* x = (const float*)d_in[0];
    const int* ei = (const int*)d_in[1];  // int32 on device
    const float* W1 = (const float*)d_in[2];
    const float* b1 = (const float*)d_in[3];
    const float* W2 = (const float*)d_in[4];
    const float* b2 = (const float*)d_in[5];
    const float* W3 = (const float*)d_in[6];
    const float* b3 = (const float*)d_in[7];
    const float* W4 = (const float*)d_in[8];
    const float* b4 = (const float*)d_in[9];

    int n = in_sizes[0] / 128;
    int e = in_sizes[1] / 2;
    const int* s32 = ei;
    const int* d32 = ei + e;
    int nbkt = (n + CBN - 1) >> CBSH;  // 196

    char* w = (char*)d_ws;
    auto alloc = [&](size_t bytes) {
        char* p = w;
        w += (bytes + 255) & ~(size_t)255;
        return p;
    };
    int* rowptr = (int*)alloc(((size_t)n + 1) * 4);
    float* dinv = (float*)alloc((size_t)n * 4);
    int* csr = (int*)alloc((size_t)e * 4);
    int* H = (int*)alloc((size_t)NB2 * nbkt * 4);
    int* bstart = (int*)alloc(((size_t)nbkt + 1) * 4);
    uint4* Gu1 = (uint4*)alloc((size_t)n * 4 * 16);   // 4 fp16 chunks; aliases slab
    uint4* Gu2 = (uint4*)alloc((size_t)n * 4 * 16);
    float4* A = (float4*)alloc((size_t)n * 4 * 32);   // 4 fp32 chunk planes (float4 pairs)
    unsigned* slab = (unsigned*)Gu1;

    int nb = (n + BLK - 1) / BLK;   // 391
    int nb64 = (n + 63) / 64;       // 1563

    // CSR build
    k_cnt<<<NB2, BLK, 0, stream>>>(d32, H, e, nbkt);
    k_bsum<<<1, BLK, 0, stream>>>(H, bstart, nbkt, e);
    k_off<<<nbkt, BLK, 0, stream>>>(H, bstart, nbkt);
    k_scatter2<<<NB2, BLK, 0, stream>>>(s32, d32, H, slab, e, nbkt);
    k_build<<<nbkt, BLK, 0, stream>>>(bstart, slab, rowptr, dinv, csr, n, e);

    // layer 1: gemm F-space; agg F-space (chunk-sharded) + G2 epilogue
    k_gemm1<<<nb, BLK, 0, stream>>>(x, W1, dinv, Gu2, n);
    k_aggF<<<2 * nb, BLK, 0, stream>>>(rowptr, csr, Gu2, Gu1, dinv, b1, n);

    // layer 2: agg K-space (K=15, 2 chunks) -> A; split gemm -> G3 (3 chunks)
    k_aggK<2, 2><<<2 * nb, BLK, 0, stream>>>(rowptr, csr, Gu1, A, n);
    k_gemmS<2, 15, 20, 3><<<nb64, 192, 0, stream>>>(A, W2, b2, dinv, Gu2, n);

    // layer 3: agg (K=20, 3 chunks, CHM=4) -> A; split gemm -> G4 (4 chunks)
    k_aggK<4, 3><<<4 * nb, BLK, 0, stream>>>(rowptr, csr, Gu2, A, n);
    k_gemmS<3, 20, 27, 4><<<nb64, 256, 0, stream>>>(A, W3, b3, dinv, Gu1, n);

    // layer 4: agg (K=27, 4 chunks) -> A; split final gemm -> d_out
    k_aggK<4, 4><<<4 * nb, BLK, 0, stream>>>(rowptr, csr, Gu1, A, n);
    k_gemm4S<<<nb64, 192, 0, stream>>>(A, W4, b4, dinv, (float*)d_out, n);
}

// Round 14
// 345.515 us; speedup vs baseline: 1.5381x; 1.5381x over previous
//
#include <hip/hip_runtime.h>
#include <hip/hip_fp16.h>
#include <math.h>

#define BLK 256
#define CBSH 9           // 512 nodes per coarse bucket (196 buckets for n=100k)
#define CBN 512
#define NCBC 256
#define NB2 512

__device__ __forceinline__ float selu_f(float x) {
    const float kScale = 1.0507009873554805f;
    const float kAlpha = 1.6732632423543772f;
    return x > 0.0f ? kScale * x : kScale * kAlpha * expm1f(x);
}

__device__ __forceinline__ float2 h2f2(unsigned u) {
    __half2 h = *reinterpret_cast<__half2*>(&u);
    return __half22float2(h);
}
__device__ __forceinline__ void h8_set(float* a, uint4 v) {
    float2 f0 = h2f2(v.x), f1 = h2f2(v.y), f2 = h2f2(v.z), f3 = h2f2(v.w);
    a[0] = f0.x; a[1] = f0.y; a[2] = f1.x; a[3] = f1.y;
    a[4] = f2.x; a[5] = f2.y; a[6] = f3.x; a[7] = f3.y;
}
__device__ __forceinline__ void h8_add(float* a, uint4 v) {
    float2 f0 = h2f2(v.x), f1 = h2f2(v.y), f2 = h2f2(v.z), f3 = h2f2(v.w);
    a[0] += f0.x; a[1] += f0.y; a[2] += f1.x; a[3] += f1.y;
    a[4] += f2.x; a[5] += f2.y; a[6] += f3.x; a[7] += f3.y;
}
__device__ __forceinline__ uint4 f8_pack(const float* a) {
    __half2 h0 = __float22half2_rn(make_float2(a[0], a[1]));
    __half2 h1 = __float22half2_rn(make_float2(a[2], a[3]));
    __half2 h2 = __float22half2_rn(make_float2(a[4], a[5]));
    __half2 h3 = __float22half2_rn(make_float2(a[6], a[7]));
    uint4 u;
    u.x = *reinterpret_cast<unsigned*>(&h0);
    u.y = *reinterpret_cast<unsigned*>(&h1);
    u.z = *reinterpret_cast<unsigned*>(&h2);
    u.w = *reinterpret_cast<unsigned*>(&h3);
    return u;
}

// ---------------- CSR build (two-pass counting sort; identical to round 9) ----------------
__global__ void k_cnt(const int* __restrict__ dst, int* __restrict__ H, int e, int nbkt) {
    __shared__ int hist[NCBC];
    int tid = threadIdx.x;
    for (int b = tid; b < nbkt; b += BLK) hist[b] = 0;
    __syncthreads();
    int per = (e + NB2 - 1) / NB2;
    int lo = blockIdx.x * per;
    int hi = min(e, lo + per);
    for (int i = lo + tid; i < hi; i += BLK) atomicAdd(&hist[dst[i] >> CBSH], 1);
    __syncthreads();
    for (int b = tid; b < nbkt; b += BLK) H[blockIdx.x * nbkt + b] = hist[b];
}

__global__ void k_bsum(const int* __restrict__ H, int* __restrict__ bstart, int nbkt, int e) {
    __shared__ int tot[NCBC];
    int tid = threadIdx.x;
    for (int b = tid; b < nbkt; b += BLK) {
        int s = 0;
        for (int i = 0; i < NB2; ++i) s += H[i * nbkt + b];
        tot[b] = s;
    }
    __syncthreads();
    if (tid == 0) {
        int acc = 0;
        for (int b = 0; b < nbkt; ++b) {
            bstart[b] = acc;
            acc += tot[b];
        }
        bstart[nbkt] = acc;
    }
}

__global__ void k_off(int* __restrict__ H, const int* __restrict__ bstart, int nbkt) {
    __shared__ int lds[BLK];
    int b = blockIdx.x, tid = threadIdx.x;
    int v0 = H[(2 * tid) * nbkt + b];
    int v1 = H[(2 * tid + 1) * nbkt + b];
    int pair = v0 + v1;
    lds[tid] = pair;
    __syncthreads();
    int val = pair;
    for (int off = 1; off < BLK; off <<= 1) {
        int t2 = (tid >= off) ? lds[tid - off] : 0;
        __syncthreads();
        val += t2;
        lds[tid] = val;
        __syncthreads();
    }
    int excl = val - pair + bstart[b];
    H[(2 * tid) * nbkt + b] = excl;
    H[(2 * tid + 1) * nbkt + b] = excl + v0;
}

__global__ void k_scatter2(const int* __restrict__ src, const int* __restrict__ dst,
                           const int* __restrict__ H, unsigned* __restrict__ slab,
                           int e, int nbkt) {
    __shared__ int cur[NCBC];
    int tid = threadIdx.x;
    for (int b = tid; b < nbkt; b += BLK) cur[b] = H[blockIdx.x * nbkt + b];
    __syncthreads();
    int per = (e + NB2 - 1) / NB2;
    int lo = blockIdx.x * per;
    int hi = min(e, lo + per);
    for (int i = lo + tid; i < hi; i += BLK) {
        int s = src[i], d = dst[i];
        int b = d >> CBSH;
        int pos = atomicAdd(&cur[b], 1);
        slab[pos] = ((unsigned)s << CBSH) | (unsigned)(d & (CBN - 1));
    }
}

__global__ void k_build(const int* __restrict__ bstart, const unsigned* __restrict__ slab,
                        int* __restrict__ rowptr, float* __restrict__ dinv,
                        int* __restrict__ csr, int n, int e) {
    __shared__ int hist[CBN];
    __shared__ int stmp[BLK];
    int b = blockIdx.x, tid = threadIdx.x;
    hist[2 * tid] = 0;
    hist[2 * tid + 1] = 0;
    __syncthreads();
    int lo = bstart[b], hi = bstart[b + 1];
    for (int i = lo + tid; i < hi; i += BLK) atomicAdd(&hist[slab[i] & (CBN - 1)], 1);
    __syncthreads();
    int h0 = hist[2 * tid], h1 = hist[2 * tid + 1];
    int pair = h0 + h1;
    stmp[tid] = pair;
    __syncthreads();
    int val = pair;
    for (int off = 1; off < BLK; off <<= 1) {
        int t2 = (tid >= off) ? stmp[tid - off] : 0;
        __syncthreads();
        val += t2;
        stmp[tid] = val;
        __syncthreads();
    }
    int e0 = lo + val - pair;
    int e1 = e0 + h0;
    hist[2 * tid] = e0;
    hist[2 * tid + 1] = e1;
    int node0 = b << CBSH;
    int nA = node0 + 2 * tid, nB = nA + 1;
    if (nA < n) { rowptr[nA] = e0; dinv[nA] = rsqrtf((float)(h0 + 1)); }
    if (nB < n) { rowptr[nB] = e1; dinv[nB] = rsqrtf((float)(h1 + 1)); }
    if (b == 0 && tid == 0) rowptr[n] = e;
    __syncthreads();
    for (int i = lo + tid; i < hi; i += BLK) {
        unsigned p = slab[i];
        int pos = atomicAdd(&hist[p & (CBN - 1)], 1);
        csr[pos] = (int)(p >> CBSH);
    }
}

// ---------------- layer compute (round-9 structure) ----------------
// hs[i,0..F) = fp16( dinv[i] * (act(xin[i,0..K)) @ W) ); rows at SO halves, zero-pad to F8.
template <int K, int KP, int F, int SI, int SO, bool FUSE_IN>
__global__ void k_gemm(const float* __restrict__ xin, const float* __restrict__ W,
                       const float* __restrict__ bprev, const float* __restrict__ dinv,
                       __half* __restrict__ hs, int n) {
    constexpr int F8 = (F + 7) & ~7;
    int i = blockIdx.x * BLK + threadIdx.x;
    if (i >= n) return;
    const float* xr = xin + (size_t)i * SI;
    float di = dinv[i];
    float accf[F8];
#pragma unroll
    for (int f = 0; f < F8; ++f) accf[f] = 0.0f;
#pragma unroll
    for (int k4 = 0; k4 < KP / 4; ++k4) {
        float4 xv = *reinterpret_cast<const float4*>(xr + k4 * 4);
        float xs4[4] = {xv.x, xv.y, xv.z, xv.w};
#pragma unroll
        for (int j = 0; j < 4; ++j) {
            const int k = k4 * 4 + j;
            if (k < K) {
                float xval = xs4[j];
                if (FUSE_IN) xval = selu_f(di * xval + bprev[k]);  // prev-layer epilogue
#pragma unroll
                for (int f = 0; f < F; ++f) accf[f] = fmaf(xval, W[k * F + f], accf[f]);
            }
        }
    }
#pragma unroll
    for (int f = 0; f < F; ++f) accf[f] *= di;
    __half2* ro2 = reinterpret_cast<__half2*>(hs + (size_t)i * SO);
#pragma unroll
    for (int f2 = 0; f2 < F8 / 2; ++f2)
        ro2[f2] = __float22half2_rn(make_float2(accf[2 * f2], accf[2 * f2 + 1]));
}

// Layer-4 gemm: same AoS-reading body, output = 5 chunk-SoA fp16 planes (16B rows).
__global__ void k_gemm4(const float* __restrict__ xin, const float* __restrict__ W,
                        const float* __restrict__ bprev, const float* __restrict__ dinv,
                        uint4* __restrict__ G, int n) {
    constexpr int K = 27, F = 36;
    int i = blockIdx.x * BLK + threadIdx.x;
    if (i >= n) return;
    const float* xr = xin + (size_t)i * 32;
    float di = dinv[i];
    float accf[40];
#pragma unroll
    for (int f = 0; f < 40; ++f) accf[f] = 0.0f;
#pragma unroll
    for (int k4 = 0; k4 < 7; ++k4) {
        float4 xv = *reinterpret_cast<const float4*>(xr + k4 * 4);
        float xs4[4] = {xv.x, xv.y, xv.z, xv.w};
#pragma unroll
        for (int j = 0; j < 4; ++j) {
            const int k = k4 * 4 + j;
            if (k < K) {
                float xval = selu_f(di * xs4[j] + bprev[k]);
#pragma unroll
                for (int f = 0; f < F; ++f) accf[f] = fmaf(xval, W[k * F + f], accf[f]);
            }
        }
    }
#pragma unroll
    for (int f = 0; f < F; ++f) accf[f] *= di;
#pragma unroll
    for (int f = F; f < 40; ++f) accf[f] = 0.0f;
#pragma unroll
    for (int c = 0; c < 5; ++c) G[(size_t)c * n + i] = f8_pack(accf + c * 8);
}

// CSR gather on fp16 AoS rows: G lanes/node, lane chunk = uint4 (8 halves), fp32 accum.
// Unroll-8 folded into 4 accumulators; csr via non-temporal loads. (round-9 verbatim)
template <int F, int S /*halves*/, int G, int SOUT>
__global__ void k_agg(const int* __restrict__ rowptr, const int* __restrict__ csr,
                      const __half* __restrict__ hs, float* __restrict__ out, int n) {
    constexpr int NPW = 64 / G;
    constexpr int CH = ((F + 7) & ~7) / 8;
    int lane = threadIdx.x & 63;
    int g = lane / G;
    int fl = lane & (G - 1);
    int wid = (blockIdx.x * BLK + threadIdx.x) >> 6;
    int d = wid * NPW + g;
    if (d >= n || fl >= CH) return;
    int beg = rowptr[d], end = rowptr[d + 1];
    auto rowp = [&](int r) {
        return reinterpret_cast<const uint4*>(hs + (size_t)r * S) + fl;
    };
    float s0[8], s1[8] = {0}, s2[8] = {0}, s3[8] = {0};
    h8_set(s0, *rowp(d));  // self
    int p = beg;
    for (; p + 8 <= end; p += 8) {
        int e0 = __builtin_nontemporal_load(csr + p);
        int e1 = __builtin_nontemporal_load(csr + p + 1);
        int e2 = __builtin_nontemporal_load(csr + p + 2);
        int e3 = __builtin_nontemporal_load(csr + p + 3);
        int e4 = __builtin_nontemporal_load(csr + p + 4);
        int e5 = __builtin_nontemporal_load(csr + p + 5);
        int e6 = __builtin_nontemporal_load(csr + p + 6);
        int e7 = __builtin_nontemporal_load(csr + p + 7);
        uint4 v0 = *rowp(e0), v1 = *rowp(e1), v2 = *rowp(e2), v3 = *rowp(e3);
        uint4 v4 = *rowp(e4), v5 = *rowp(e5), v6 = *rowp(e6), v7 = *rowp(e7);
        h8_add(s0, v0); h8_add(s1, v1); h8_add(s2, v2); h8_add(s3, v3);
        h8_add(s0, v4); h8_add(s1, v5); h8_add(s2, v6); h8_add(s3, v7);
    }
    for (; p + 4 <= end; p += 4) {
        int e0 = __builtin_nontemporal_load(csr + p);
        int e1 = __builtin_nontemporal_load(csr + p + 1);
        int e2 = __builtin_nontemporal_load(csr + p + 2);
        int e3 = __builtin_nontemporal_load(csr + p + 3);
        uint4 v0 = *rowp(e0), v1 = *rowp(e1), v2 = *rowp(e2), v3 = *rowp(e3);
        h8_add(s0, v0); h8_add(s1, v1); h8_add(s2, v2); h8_add(s3, v3);
    }
    for (; p < end; ++p) h8_add(s0, *rowp(__builtin_nontemporal_load(csr + p)));
    float sum[8];
#pragma unroll
    for (int j = 0; j < 8; ++j) sum[j] = (s0[j] + s1[j]) + (s2[j] + s3[j]);
    float* op = out + (size_t)d * SOUT + fl * 8;
    *reinterpret_cast<float4*>(op) = make_float4(sum[0], sum[1], sum[2], sum[3]);
    *reinterpret_cast<float4*>(op + 4) = make_float4(sum[4], sum[5], sum[6], sum[7]);
}

// Layer-4 agg, chunk-sharded: class cls = bid&7 (~XCD id); classes 0-4 gather one
// 1.6MB SoA plane each (L2-resident per XCD); fused final epilogue -> d_out slice.
__global__ void k_agg4s(const int* __restrict__ rowptr, const int* __restrict__ csr,
                        const uint4* __restrict__ G, float* __restrict__ out,
                        const float* __restrict__ dinv, const float* __restrict__ bias,
                        int n) {
    int cls = blockIdx.x & 7;
    if (cls >= 5) return;
    int d = (blockIdx.x >> 3) * BLK + threadIdx.x;
    if (d >= n) return;
    const uint4* gs = G + (size_t)cls * n;
    float a0[8], a1[8] = {0}, a2[8] = {0}, a3[8] = {0};
    h8_set(a0, gs[d]);  // self
    int p = rowptr[d], end = rowptr[d + 1];
    for (; p + 4 <= end; p += 4) {
        int r0 = __builtin_nontemporal_load(csr + p);
        int r1 = __builtin_nontemporal_load(csr + p + 1);
        int r2 = __builtin_nontemporal_load(csr + p + 2);
        int r3 = __builtin_nontemporal_load(csr + p + 3);
        uint4 v0 = gs[r0], v1 = gs[r1], v2 = gs[r2], v3 = gs[r3];
        h8_add(a0, v0); h8_add(a1, v1); h8_add(a2, v2); h8_add(a3, v3);
    }
    for (; p < end; ++p) h8_add(a0, gs[__builtin_nontemporal_load(csr + p)]);
    float di = dinv[d];
    if (cls < 4) {
        float r[8];
#pragma unroll
        for (int j = 0; j < 8; ++j) {
            float s = (a0[j] + a1[j]) + (a2[j] + a3[j]);
            r[j] = selu_f(di * s + bias[cls * 8 + j]);
        }
        float* op = out + (size_t)d * 36 + cls * 8;
        *reinterpret_cast<float4*>(op) = make_float4(r[0], r[1], r[2], r[3]);
        *reinterpret_cast<float4*>(op + 4) = make_float4(r[4], r[5], r[6], r[7]);
    } else {
        float r[4];
#pragma unroll
        for (int j = 0; j < 4; ++j) {
            float s = (a0[j] + a1[j]) + (a2[j] + a3[j]);
            r[j] = selu_f(di * s + bias[32 + j]);
        }
        *reinterpret_cast<float4*>(out + (size_t)d * 36 + 32) =
            make_float4(r[0], r[1], r[2], r[3]);
    }
}

extern "C" void kernel_launch(void* const* d_in, const int* in_sizes, int n_in,
                              void* d_out, int out_size, void* d_ws, size_t ws_size,
                              hipStream_t stream) {
    const float* x = (const float*)d_in[0];
    const int* ei = (const int*)d_in[1];  // int32 on device
    const float* W1 = (const float*)d_in[2];
    const float* b1 = (const float*)d_in[3];
    const float* W2 = (const float*)d_in[4];
    const float* b2 = (const float*)d_in[5];
    const float* W3 = (const float*)d_in[6];
    const float* b3 = (const float*)d_in[7];
    const float* W4 = (const float*)d_in[8];
    const float* b4 = (const float*)d_in[9];

    int n = in_sizes[0] / 128;
    int e = in_sizes[1] / 2;
    const int* s32 = ei;
    const int* d32 = ei + e;
    int nbkt = (n + CBN - 1) >> CBSH;  // 196

    char* w = (char*)d_ws;
    auto alloc = [&](size_t bytes) {
        char* p = w;
        w += (bytes + 255) & ~(size_t)255;
        return p;
    };
    int* rowptr = (int*)alloc(((size_t)n + 1) * 4);
    float* dinv = (float*)alloc((size_t)n * 4);
    int* csr = (int*)alloc((size_t)e * 4);
    int* H = (int*)alloc((size_t)NB2 * nbkt * 4);
    int* bstart = (int*)alloc(((size_t)nbkt + 1) * 4);
    __half* bufA = (__half*)alloc((size_t)n * 40 * 2);  // hs / layer-4 SoA planes; aliases slab
    float* bufB = (float*)alloc((size_t)n * 32 * 4);    // agg out / gemm in (fp32)
    unsigned* slab = (unsigned*)bufA;   // e*4 = 6.4MB <= 8MB
    uint4* G4 = (uint4*)bufA;           // layer-4: 5 planes x n x 16B = 8MB

    int nb = (n + BLK - 1) / BLK;

    // CSR build
    k_cnt<<<NB2, BLK, 0, stream>>>(d32, H, e, nbkt);
    k_bsum<<<1, BLK, 0, stream>>>(H, bstart, nbkt, e);
    k_off<<<nbkt, BLK, 0, stream>>>(H, bstart, nbkt);
    k_scatter2<<<NB2, BLK, 0, stream>>>(s32, d32, H, slab, e, nbkt);
    k_build<<<nbkt, BLK, 0, stream>>>(bstart, slab, rowptr, dinv, csr, n, e);

    // agg grids (rounds 8/9): nodes/block = 4 waves * (64/G)
    int ab1 = (n + 127) / 128;  // G=2
    int ab2 = (n + 63) / 64;    // G=4

    // layer 1: x[.,128] @ W1 -> hs1 fp16 (stride 16h); agg -> bufB fp32 (stride 16)
    k_gemm<128, 128, 15, 128, 16, false><<<nb, BLK, 0, stream>>>(x, W1, nullptr, dinv, bufA, n);
    k_agg<15, 16, 2, 16><<<ab1, BLK, 0, stream>>>(rowptr, csr, bufA, bufB, n);

    // layer 2: hs2 stride 32h; agg out stride 32
    k_gemm<15, 16, 20, 16, 32, true><<<nb, BLK, 0, stream>>>(bufB, W2, b1, dinv, bufA, n);
    k_agg<20, 32, 4, 32><<<ab2, BLK, 0, stream>>>(rowptr, csr, bufA, bufB, n);

    // layer 3
    k_gemm<20, 20, 27, 32, 32, true><<<nb, BLK, 0, stream>>>(bufB, W3, b2, dinv, bufA, n);
    k_agg<27, 32, 4, 32><<<ab2, BLK, 0, stream>>>(rowptr, csr, bufA, bufB, n);

    // layer 4: gemm -> 5 chunk-SoA fp16 planes; sharded agg + fused epilogue -> d_out
    k_gemm4<<<nb, BLK, 0, stream>>>(bufB, W4, b3, dinv, G4, n);
    k_agg4s<<<8 * nb, BLK, 0, stream>>>(rowptr, csr, G4, (float*)d_out, dinv, b4, n);
}

// Round 15
// 279.585 us; speedup vs baseline: 1.9008x; 1.2358x over previous
//
#include <hip/hip_runtime.h>
#include <hip/hip_fp16.h>
#include <math.h>

#define BLK 256
#define CBSH 9           // 512 nodes per coarse bucket (196 buckets for n=100k)
#define CBN 512
#define NCBC 256
#define NB2 512

__device__ __forceinline__ float selu_f(float x) {
    const float kScale = 1.0507009873554805f;
    const float kAlpha = 1.6732632423543772f;
    return x > 0.0f ? kScale * x : kScale * kAlpha * expm1f(x);
}

__device__ __forceinline__ float2 h2f2(unsigned u) {
    __half2 h = *reinterpret_cast<__half2*>(&u);
    return __half22float2(h);
}
__device__ __forceinline__ void h8_set(float* a, uint4 v) {
    float2 f0 = h2f2(v.x), f1 = h2f2(v.y), f2 = h2f2(v.z), f3 = h2f2(v.w);
    a[0] = f0.x; a[1] = f0.y; a[2] = f1.x; a[3] = f1.y;
    a[4] = f2.x; a[5] = f2.y; a[6] = f3.x; a[7] = f3.y;
}
__device__ __forceinline__ void h8_add(float* a, uint4 v) {
    float2 f0 = h2f2(v.x), f1 = h2f2(v.y), f2 = h2f2(v.z), f3 = h2f2(v.w);
    a[0] += f0.x; a[1] += f0.y; a[2] += f1.x; a[3] += f1.y;
    a[4] += f2.x; a[5] += f2.y; a[6] += f3.x; a[7] += f3.y;
}

// ---------------- CSR build (two-pass counting sort + fused build; round-9 verbatim) ----------------
__global__ void k_cnt(const int* __restrict__ dst, int* __restrict__ H, int e, int nbkt) {
    __shared__ int hist[NCBC];
    int tid = threadIdx.x;
    for (int b = tid; b < nbkt; b += BLK) hist[b] = 0;
    __syncthreads();
    int per = (e + NB2 - 1) / NB2;
    int lo = blockIdx.x * per;
    int hi = min(e, lo + per);
    for (int i = lo + tid; i < hi; i += BLK) atomicAdd(&hist[dst[i] >> CBSH], 1);
    __syncthreads();
    for (int b = tid; b < nbkt; b += BLK) H[blockIdx.x * nbkt + b] = hist[b];
}

__global__ void k_bsum(const int* __restrict__ H, int* __restrict__ bstart, int nbkt, int e) {
    __shared__ int tot[NCBC];
    int tid = threadIdx.x;
    for (int b = tid; b < nbkt; b += BLK) {
        int s = 0;
        for (int i = 0; i < NB2; ++i) s += H[i * nbkt + b];
        tot[b] = s;
    }
    __syncthreads();
    if (tid == 0) {
        int acc = 0;
        for (int b = 0; b < nbkt; ++b) {
            bstart[b] = acc;
            acc += tot[b];
        }
        bstart[nbkt] = acc;  // == e
    }
}

__global__ void k_off(int* __restrict__ H, const int* __restrict__ bstart, int nbkt) {
    __shared__ int lds[BLK];
    int b = blockIdx.x, tid = threadIdx.x;
    int v0 = H[(2 * tid) * nbkt + b];
    int v1 = H[(2 * tid + 1) * nbkt + b];
    int pair = v0 + v1;
    lds[tid] = pair;
    __syncthreads();
    int val = pair;
    for (int off = 1; off < BLK; off <<= 1) {
        int t2 = (tid >= off) ? lds[tid - off] : 0;
        __syncthreads();
        val += t2;
        lds[tid] = val;
        __syncthreads();
    }
    int excl = val - pair + bstart[b];
    H[(2 * tid) * nbkt + b] = excl;
    H[(2 * tid + 1) * nbkt + b] = excl + v0;
}

__global__ void k_scatter2(const int* __restrict__ src, const int* __restrict__ dst,
                           const int* __restrict__ H, unsigned* __restrict__ slab,
                           int e, int nbkt) {
    __shared__ int cur[NCBC];
    int tid = threadIdx.x;
    for (int b = tid; b < nbkt; b += BLK) cur[b] = H[blockIdx.x * nbkt + b];
    __syncthreads();
    int per = (e + NB2 - 1) / NB2;
    int lo = blockIdx.x * per;
    int hi = min(e, lo + per);
    for (int i = lo + tid; i < hi; i += BLK) {
        int s = src[i], d = dst[i];
        int b = d >> CBSH;
        int pos = atomicAdd(&cur[b], 1);
        slab[pos] = ((unsigned)s << CBSH) | (unsigned)(d & (CBN - 1));
    }
}

__global__ void k_build(const int* __restrict__ bstart, const unsigned* __restrict__ slab,
                        int* __restrict__ rowptr, float* __restrict__ dinv,
                        int* __restrict__ csr, int n, int e) {
    __shared__ int hist[CBN];
    __shared__ int stmp[BLK];
    int b = blockIdx.x, tid = threadIdx.x;
    hist[2 * tid] = 0;
    hist[2 * tid + 1] = 0;
    __syncthreads();
    int lo = bstart[b], hi = bstart[b + 1];
    for (int i = lo + tid; i < hi; i += BLK) atomicAdd(&hist[slab[i] & (CBN - 1)], 1);
    __syncthreads();
    int h0 = hist[2 * tid], h1 = hist[2 * tid + 1];
    int pair = h0 + h1;
    stmp[tid] = pair;
    __syncthreads();
    int val = pair;
    for (int off = 1; off < BLK; off <<= 1) {
        int t2 = (tid >= off) ? stmp[tid - off] : 0;
        __syncthreads();
        val += t2;
        stmp[tid] = val;
        __syncthreads();
    }
    int e0 = lo + val - pair;
    int e1 = e0 + h0;
    hist[2 * tid] = e0;
    hist[2 * tid + 1] = e1;
    int node0 = b << CBSH;
    int nA = node0 + 2 * tid, nB = nA + 1;
    if (nA < n) { rowptr[nA] = e0; dinv[nA] = rsqrtf((float)(h0 + 1)); }
    if (nB < n) { rowptr[nB] = e1; dinv[nB] = rsqrtf((float)(h1 + 1)); }
    if (b == 0 && tid == 0) rowptr[n] = e;
    __syncthreads();
    for (int i = lo + tid; i < hi; i += BLK) {
        unsigned p = slab[i];
        int pos = atomicAdd(&hist[p & (CBN - 1)], 1);
        csr[pos] = (int)(p >> CBSH);
    }
}

// ---------------- layer compute (round-8 structure verbatim) ----------------
// hs[i,0..F) = fp16( dinv[i] * (act(xin[i,0..K)) @ W) ); rows at SO halves, zero-pad to F8.
template <int K, int KP, int F, int SI, int SO, bool FUSE_IN>
__global__ void k_gemm(const float* __restrict__ xin, const float* __restrict__ W,
                       const float* __restrict__ bprev, const float* __restrict__ dinv,
                       __half* __restrict__ hs, int n) {
    constexpr int F8 = (F + 7) & ~7;
    int i = blockIdx.x * BLK + threadIdx.x;
    if (i >= n) return;
    const float* xr = xin + (size_t)i * SI;
    float di = dinv[i];
    float accf[F8];
#pragma unroll
    for (int f = 0; f < F8; ++f) accf[f] = 0.0f;
#pragma unroll
    for (int k4 = 0; k4 < KP / 4; ++k4) {
        float4 xv = *reinterpret_cast<const float4*>(xr + k4 * 4);
        float xs4[4] = {xv.x, xv.y, xv.z, xv.w};
#pragma unroll
        for (int j = 0; j < 4; ++j) {
            const int k = k4 * 4 + j;
            if (k < K) {
                float xval = xs4[j];
                if (FUSE_IN) xval = selu_f(di * xval + bprev[k]);  // prev-layer epilogue
#pragma unroll
                for (int f = 0; f < F; ++f) accf[f] = fmaf(xval, W[k * F + f], accf[f]);
            }
        }
    }
#pragma unroll
    for (int f = 0; f < F; ++f) accf[f] *= di;
    __half2* ro2 = reinterpret_cast<__half2*>(hs + (size_t)i * SO);
#pragma unroll
    for (int f2 = 0; f2 < F8 / 2; ++f2)
        ro2[f2] = __float22half2_rn(make_float2(accf[2 * f2], accf[2 * f2 + 1]));
}

// CSR gather on fp16 rows: G lanes/node, lane chunk = uint4 (8 halves), fp32 accum.
// Unroll-8 into 4 accumulators; csr via non-temporal loads. LAST fuses final epilogue.
template <int F, int S /*halves*/, int G, int SOUT, bool LAST>
__global__ void k_agg(const int* __restrict__ rowptr, const int* __restrict__ csr,
                      const __half* __restrict__ hs, float* __restrict__ out,
                      const float* __restrict__ dinv, const float* __restrict__ bias,
                      int n) {
    constexpr int NPW = 64 / G;
    constexpr int CH = ((F + 7) & ~7) / 8;
    int lane = threadIdx.x & 63;
    int g = lane / G;
    int fl = lane & (G - 1);
    int wid = (blockIdx.x * BLK + threadIdx.x) >> 6;
    int d = wid * NPW + g;
    if (d >= n || fl >= CH) return;
    int beg = rowptr[d], end = rowptr[d + 1];
    auto rowp = [&](int r) {
        return reinterpret_cast<const uint4*>(hs + (size_t)r * S) + fl;
    };
    float s0[8], s1[8] = {0}, s2[8] = {0}, s3[8] = {0};
    h8_set(s0, *rowp(d));  // self
    int p = beg;
    for (; p + 8 <= end; p += 8) {
        int e0 = __builtin_nontemporal_load(csr + p);
        int e1 = __builtin_nontemporal_load(csr + p + 1);
        int e2 = __builtin_nontemporal_load(csr + p + 2);
        int e3 = __builtin_nontemporal_load(csr + p + 3);
        int e4 = __builtin_nontemporal_load(csr + p + 4);
        int e5 = __builtin_nontemporal_load(csr + p + 5);
        int e6 = __builtin_nontemporal_load(csr + p + 6);
        int e7 = __builtin_nontemporal_load(csr + p + 7);
        uint4 v0 = *rowp(e0), v1 = *rowp(e1), v2 = *rowp(e2), v3 = *rowp(e3);
        uint4 v4 = *rowp(e4), v5 = *rowp(e5), v6 = *rowp(e6), v7 = *rowp(e7);
        h8_add(s0, v0); h8_add(s1, v1); h8_add(s2, v2); h8_add(s3, v3);
        h8_add(s0, v4); h8_add(s1, v5); h8_add(s2, v6); h8_add(s3, v7);
    }
    for (; p + 4 <= end; p += 4) {
        int e0 = __builtin_nontemporal_load(csr + p);
        int e1 = __builtin_nontemporal_load(csr + p + 1);
        int e2 = __builtin_nontemporal_load(csr + p + 2);
        int e3 = __builtin_nontemporal_load(csr + p + 3);
        uint4 v0 = *rowp(e0), v1 = *rowp(e1), v2 = *rowp(e2), v3 = *rowp(e3);
        h8_add(s0, v0); h8_add(s1, v1); h8_add(s2, v2); h8_add(s3, v3);
    }
    for (; p < end; ++p) h8_add(s0, *rowp(__builtin_nontemporal_load(csr + p)));
    float sum[8];
#pragma unroll
    for (int j = 0; j < 8; ++j) sum[j] = (s0[j] + s1[j]) + (s2[j] + s3[j]);
    if (LAST) {
        float dv = dinv[d];
        float r[8];
#pragma unroll
        for (int j = 0; j < 8; ++j) {
            int col = fl * 8 + j;
            r[j] = (col < F) ? selu_f(dv * sum[j] + bias[col]) : 0.0f;
        }
        float* op = out + (size_t)d * F + fl * 8;
        *reinterpret_cast<float4*>(op) = make_float4(r[0], r[1], r[2], r[3]);
        if (fl * 8 + 4 < F)
            *reinterpret_cast<float4*>(op + 4) = make_float4(r[4], r[5], r[6], r[7]);
    } else {
        float* op = out + (size_t)d * SOUT + fl * 8;
        *reinterpret_cast<float4*>(op) = make_float4(sum[0], sum[1], sum[2], sum[3]);
        *reinterpret_cast<float4*>(op + 4) = make_float4(sum[4], sum[5], sum[6], sum[7]);
    }
}

extern "C" void kernel_launch(void* const* d_in, const int* in_sizes, int n_in,
                              void* d_out, int out_size, void* d_ws, size_t ws_size,
                              hipStream_t stream) {
    const float* x = (const float*)d_in[0];
    const int* ei = (const int*)d_in[1];  // int32 on device
    const float* W1 = (const float*)d_in[2];
    const float* b1 = (const float*)d_in[3];
    const float* W2 = (const float*)d_in[4];
    const float* b2 = (const float*)d_in[5];
    const float* W3 = (const float*)d_in[6];
    const float* b3 = (const float*)d_in[7];
    const float* W4 = (const float*)d_in[8];
    const float* b4 = (const float*)d_in[9];

    int n = in_sizes[0] / 128;
    int e = in_sizes[1] / 2;
    const int* s32 = ei;
    const int* d32 = ei + e;
    int nbkt = (n + CBN - 1) >> CBSH;  // 196

    char* w = (char*)d_ws;
    auto alloc = [&](size_t bytes) {
        char* p = w;
        w += (bytes + 255) & ~(size_t)255;
        return p;
    };
    int* rowptr = (int*)alloc(((size_t)n + 1) * 4);
    float* dinv = (float*)alloc((size_t)n * 4);
    int* csr = (int*)alloc((size_t)e * 4);
    int* H = (int*)alloc((size_t)NB2 * nbkt * 4);
    int* bstart = (int*)alloc(((size_t)nbkt + 1) * 4);
    __half* bufA = (__half*)alloc((size_t)n * 40 * 2);  // hs (max stride 40h); aliases slab
    float* bufB = (float*)alloc((size_t)n * 32 * 4);    // agg out / gemm in (fp32)
    unsigned* slab = (unsigned*)bufA;   // e*4 = 6.4MB <= 8MB

    int nb = (n + BLK - 1) / BLK;

    // CSR build: counting sort + fused build (round-9 chain)
    k_cnt<<<NB2, BLK, 0, stream>>>(d32, H, e, nbkt);
    k_bsum<<<1, BLK, 0, stream>>>(H, bstart, nbkt, e);
    k_off<<<nbkt, BLK, 0, stream>>>(H, bstart, nbkt);
    k_scatter2<<<NB2, BLK, 0, stream>>>(s32, d32, H, slab, e, nbkt);
    k_build<<<nbkt, BLK, 0, stream>>>(bstart, slab, rowptr, dinv, csr, n, e);

    // agg grids: nodes/block = 4 waves * (64/G)
    int ab1 = (n + 127) / 128;  // G=2
    int ab2 = (n + 63) / 64;    // G=4
    int ab4 = (n + 31) / 32;    // G=8 (layer 4)

    // layer 1: x[.,128] @ W1 -> hs1 fp16 (stride 16h); agg -> bufB fp32 (stride 16)
    k_gemm<128, 128, 15, 128, 16, false><<<nb, BLK, 0, stream>>>(x, W1, nullptr, dinv, bufA, n);
    k_agg<15, 16, 2, 16, false><<<ab1, BLK, 0, stream>>>(rowptr, csr, bufA, bufB, dinv, nullptr, n);

    // layer 2: hs2 stride 32h; agg out stride 32
    k_gemm<15, 16, 20, 16, 32, true><<<nb, BLK, 0, stream>>>(bufB, W2, b1, dinv, bufA, n);
    k_agg<20, 32, 4, 32, false><<<ab2, BLK, 0, stream>>>(rowptr, csr, bufA, bufB, dinv, nullptr, n);

    // layer 3
    k_gemm<20, 20, 27, 32, 32, true><<<nb, BLK, 0, stream>>>(bufB, W3, b2, dinv, bufA, n);
    k_agg<27, 32, 4, 32, false><<<ab2, BLK, 0, stream>>>(rowptr, csr, bufA, bufB, dinv, nullptr, n);

    // layer 4: hs4 stride 40h (80B rows); agg fuses final epilogue -> d_out  (round-8 path)
    k_gemm<27, 28, 36, 32, 40, true><<<nb, BLK, 0, stream>>>(bufB, W4, b3, dinv, bufA, n);
    k_agg<36, 40, 8, 36, true><<<ab4, BLK, 0, stream>>>(rowptr, csr, bufA, (float*)d_out, dinv, b4, n);
}

// Round 16
// 271.528 us; speedup vs baseline: 1.9572x; 1.0297x over previous
//
#include <hip/hip_runtime.h>
#include <hip/hip_fp16.h>
#include <math.h>

#define BLK 256
#define CBSH 9           // 512 nodes per coarse bucket (196 buckets for n=100k)
#define CBN 512
#define NCBC 256
#define NB2 512

__device__ __forceinline__ float selu_f(float x) {
    const float kScale = 1.0507009873554805f;
    const float kAlpha = 1.6732632423543772f;
    return x > 0.0f ? kScale * x : kScale * kAlpha * expm1f(x);
}

__device__ __forceinline__ float2 h2f2(unsigned u) {
    __half2 h = *reinterpret_cast<__half2*>(&u);
    return __half22float2(h);
}
__device__ __forceinline__ void h8_set(float* a, uint4 v) {
    float2 f0 = h2f2(v.x), f1 = h2f2(v.y), f2 = h2f2(v.z), f3 = h2f2(v.w);
    a[0] = f0.x; a[1] = f0.y; a[2] = f1.x; a[3] = f1.y;
    a[4] = f2.x; a[5] = f2.y; a[6] = f3.x; a[7] = f3.y;
}
__device__ __forceinline__ void h8_add(float* a, uint4 v) {
    float2 f0 = h2f2(v.x), f1 = h2f2(v.y), f2 = h2f2(v.z), f3 = h2f2(v.w);
    a[0] += f0.x; a[1] += f0.y; a[2] += f1.x; a[3] += f1.y;
    a[4] += f2.x; a[5] += f2.y; a[6] += f3.x; a[7] += f3.y;
}

// ---------------- CSR build (two-pass counting sort + fused build; round-15 verbatim) ----------------
__global__ void k_cnt(const int* __restrict__ dst, int* __restrict__ H, int e, int nbkt) {
    __shared__ int hist[NCBC];
    int tid = threadIdx.x;
    for (int b = tid; b < nbkt; b += BLK) hist[b] = 0;
    __syncthreads();
    int per = (e + NB2 - 1) / NB2;
    int lo = blockIdx.x * per;
    int hi = min(e, lo + per);
    for (int i = lo + tid; i < hi; i += BLK) atomicAdd(&hist[dst[i] >> CBSH], 1);
    __syncthreads();
    for (int b = tid; b < nbkt; b += BLK) H[blockIdx.x * nbkt + b] = hist[b];
}

__global__ void k_bsum(const int* __restrict__ H, int* __restrict__ bstart, int nbkt, int e) {
    __shared__ int tot[NCBC];
    int tid = threadIdx.x;
    for (int b = tid; b < nbkt; b += BLK) {
        int s = 0;
        for (int i = 0; i < NB2; ++i) s += H[i * nbkt + b];
        tot[b] = s;
    }
    __syncthreads();
    if (tid == 0) {
        int acc = 0;
        for (int b = 0; b < nbkt; ++b) {
            bstart[b] = acc;
            acc += tot[b];
        }
        bstart[nbkt] = acc;  // == e
    }
}

__global__ void k_off(int* __restrict__ H, const int* __restrict__ bstart, int nbkt) {
    __shared__ int lds[BLK];
    int b = blockIdx.x, tid = threadIdx.x;
    int v0 = H[(2 * tid) * nbkt + b];
    int v1 = H[(2 * tid + 1) * nbkt + b];
    int pair = v0 + v1;
    lds[tid] = pair;
    __syncthreads();
    int val = pair;
    for (int off = 1; off < BLK; off <<= 1) {
        int t2 = (tid >= off) ? lds[tid - off] : 0;
        __syncthreads();
        val += t2;
        lds[tid] = val;
        __syncthreads();
    }
    int excl = val - pair + bstart[b];
    H[(2 * tid) * nbkt + b] = excl;
    H[(2 * tid + 1) * nbkt + b] = excl + v0;
}

__global__ void k_scatter2(const int* __restrict__ src, const int* __restrict__ dst,
                           const int* __restrict__ H, unsigned* __restrict__ slab,
                           int e, int nbkt) {
    __shared__ int cur[NCBC];
    int tid = threadIdx.x;
    for (int b = tid; b < nbkt; b += BLK) cur[b] = H[blockIdx.x * nbkt + b];
    __syncthreads();
    int per = (e + NB2 - 1) / NB2;
    int lo = blockIdx.x * per;
    int hi = min(e, lo + per);
    for (int i = lo + tid; i < hi; i += BLK) {
        int s = src[i], d = dst[i];
        int b = d >> CBSH;
        int pos = atomicAdd(&cur[b], 1);
        slab[pos] = ((unsigned)s << CBSH) | (unsigned)(d & (CBN - 1));
    }
}

__global__ void k_build(const int* __restrict__ bstart, const unsigned* __restrict__ slab,
                        int* __restrict__ rowptr, float* __restrict__ dinv,
                        int* __restrict__ csr, int n, int e) {
    __shared__ int hist[CBN];
    __shared__ int stmp[BLK];
    int b = blockIdx.x, tid = threadIdx.x;
    hist[2 * tid] = 0;
    hist[2 * tid + 1] = 0;
    __syncthreads();
    int lo = bstart[b], hi = bstart[b + 1];
    for (int i = lo + tid; i < hi; i += BLK) atomicAdd(&hist[slab[i] & (CBN - 1)], 1);
    __syncthreads();
    int h0 = hist[2 * tid], h1 = hist[2 * tid + 1];
    int pair = h0 + h1;
    stmp[tid] = pair;
    __syncthreads();
    int val = pair;
    for (int off = 1; off < BLK; off <<= 1) {
        int t2 = (tid >= off) ? stmp[tid - off] : 0;
        __syncthreads();
        val += t2;
        stmp[tid] = val;
        __syncthreads();
    }
    int e0 = lo + val - pair;
    int e1 = e0 + h0;
    hist[2 * tid] = e0;
    hist[2 * tid + 1] = e1;
    int node0 = b << CBSH;
    int nA = node0 + 2 * tid, nB = nA + 1;
    if (nA < n) { rowptr[nA] = e0; dinv[nA] = rsqrtf((float)(h0 + 1)); }
    if (nB < n) { rowptr[nB] = e1; dinv[nB] = rsqrtf((float)(h1 + 1)); }
    if (b == 0 && tid == 0) rowptr[n] = e;
    __syncthreads();
    for (int i = lo + tid; i < hi; i += BLK) {
        unsigned p = slab[i];
        int pos = atomicAdd(&hist[p & (CBN - 1)], 1);
        csr[pos] = (int)(p >> CBSH);
    }
}

// ---------------- layer compute ----------------
// hs[i,0..F) = fp16( dinv[i] * (act(xin[i,0..K)) @ W) ); rows at SO halves, zero-pad to F8.
template <int K, int KP, int F, int SI, int SO, bool FUSE_IN>
__global__ void k_gemm(const float* __restrict__ xin, const float* __restrict__ W,
                       const float* __restrict__ bprev, const float* __restrict__ dinv,
                       __half* __restrict__ hs, int n) {
    constexpr int F8 = (F + 7) & ~7;
    int i = blockIdx.x * BLK + threadIdx.x;
    if (i >= n) return;
    const float* xr = xin + (size_t)i * SI;
    float di = dinv[i];
    float accf[F8];
#pragma unroll
    for (int f = 0; f < F8; ++f) accf[f] = 0.0f;
#pragma unroll
    for (int k4 = 0; k4 < KP / 4; ++k4) {
        float4 xv = *reinterpret_cast<const float4*>(xr + k4 * 4);
        float xs4[4] = {xv.x, xv.y, xv.z, xv.w};
#pragma unroll
        for (int j = 0; j < 4; ++j) {
            const int k = k4 * 4 + j;
            if (k < K) {
                float xval = xs4[j];
                if (FUSE_IN) xval = selu_f(di * xval + bprev[k]);  // prev-layer epilogue
#pragma unroll
                for (int f = 0; f < F; ++f) accf[f] = fmaf(xval, W[k * F + f], accf[f]);
            }
        }
    }
#pragma unroll
    for (int f = 0; f < F; ++f) accf[f] *= di;
    __half2* ro2 = reinterpret_cast<__half2*>(hs + (size_t)i * SO);
#pragma unroll
    for (int f2 = 0; f2 < F8 / 2; ++f2)
        ro2[f2] = __float22half2_rn(make_float2(accf[2 * f2], accf[2 * f2 + 1]));
}

// CSR gather on fp16 rows: exactly ACT lanes per node (non-power-of-2 ok), NPN nodes/wave.
// Lane fl gathers chunk fl (uint4 = 8 halves); fp32 accum; unroll-8 into 4 accumulators;
// csr via non-temporal loads. LAST fuses final epilogue.
template <int F, int S /*halves*/, int ACT, int NPN, int SOUT, bool LAST>
__global__ void k_agg(const int* __restrict__ rowptr, const int* __restrict__ csr,
                      const __half* __restrict__ hs, float* __restrict__ out,
                      const float* __restrict__ dinv, const float* __restrict__ bias,
                      int n) {
    int lane = threadIdx.x & 63;
    int g = lane / ACT;            // node slot within wave (const divisor -> magic mul)
    int fl = lane - g * ACT;       // chunk index, 0..ACT-1
    int wid = (blockIdx.x * BLK + threadIdx.x) >> 6;
    int d = wid * NPN + g;
    if (g >= NPN || d >= n) return;
    int beg = rowptr[d], end = rowptr[d + 1];
    auto rowp = [&](int r) {
        return reinterpret_cast<const uint4*>(hs + (size_t)r * S) + fl;
    };
    float s0[8], s1[8] = {0}, s2[8] = {0}, s3[8] = {0};
    h8_set(s0, *rowp(d));  // self
    int p = beg;
    for (; p + 8 <= end; p += 8) {
        int e0 = __builtin_nontemporal_load(csr + p);
        int e1 = __builtin_nontemporal_load(csr + p + 1);
        int e2 = __builtin_nontemporal_load(csr + p + 2);
        int e3 = __builtin_nontemporal_load(csr + p + 3);
        int e4 = __builtin_nontemporal_load(csr + p + 4);
        int e5 = __builtin_nontemporal_load(csr + p + 5);
        int e6 = __builtin_nontemporal_load(csr + p + 6);
        int e7 = __builtin_nontemporal_load(csr + p + 7);
        uint4 v0 = *rowp(e0), v1 = *rowp(e1), v2 = *rowp(e2), v3 = *rowp(e3);
        uint4 v4 = *rowp(e4), v5 = *rowp(e5), v6 = *rowp(e6), v7 = *rowp(e7);
        h8_add(s0, v0); h8_add(s1, v1); h8_add(s2, v2); h8_add(s3, v3);
        h8_add(s0, v4); h8_add(s1, v5); h8_add(s2, v6); h8_add(s3, v7);
    }
    for (; p + 4 <= end; p += 4) {
        int e0 = __builtin_nontemporal_load(csr + p);
        int e1 = __builtin_nontemporal_load(csr + p + 1);
        int e2 = __builtin_nontemporal_load(csr + p + 2);
        int e3 = __builtin_nontemporal_load(csr + p + 3);
        uint4 v0 = *rowp(e0), v1 = *rowp(e1), v2 = *rowp(e2), v3 = *rowp(e3);
        h8_add(s0, v0); h8_add(s1, v1); h8_add(s2, v2); h8_add(s3, v3);
    }
    for (; p < end; ++p) h8_add(s0, *rowp(__builtin_nontemporal_load(csr + p)));
    float sum[8];
#pragma unroll
    for (int j = 0; j < 8; ++j) sum[j] = (s0[j] + s1[j]) + (s2[j] + s3[j]);
    if (LAST) {
        float dv = dinv[d];
        float r[8];
#pragma unroll
        for (int j = 0; j < 8; ++j) {
            int col = fl * 8 + j;
            r[j] = (col < F) ? selu_f(dv * sum[j] + bias[col]) : 0.0f;
        }
        float* op = out + (size_t)d * F + fl * 8;
        *reinterpret_cast<float4*>(op) = make_float4(r[0], r[1], r[2], r[3]);
        if (fl * 8 + 4 < F)
            *reinterpret_cast<float4*>(op + 4) = make_float4(r[4], r[5], r[6], r[7]);
    } else {
        float* op = out + (size_t)d * SOUT + fl * 8;
        *reinterpret_cast<float4*>(op) = make_float4(sum[0], sum[1], sum[2], sum[3]);
        *reinterpret_cast<float4*>(op + 4) = make_float4(sum[4], sum[5], sum[6], sum[7]);
    }
}

extern "C" void kernel_launch(void* const* d_in, const int* in_sizes, int n_in,
                              void* d_out, int out_size, void* d_ws, size_t ws_size,
                              hipStream_t stream) {
    const float* x = (const float*)d_in[0];
    const int* ei = (const int*)d_in[1];  // int32 on device
    const float* W1 = (const float*)d_in[2];
    const float* b1 = (const float*)d_in[3];
    const float* W2 = (const float*)d_in[4];
    const float* b2 = (const float*)d_in[5];
    const float* W3 = (const float*)d_in[6];
    const float* b3 = (const float*)d_in[7];
    const float* W4 = (const float*)d_in[8];
    const float* b4 = (const float*)d_in[9];

    int n = in_sizes[0] / 128;
    int e = in_sizes[1] / 2;
    const int* s32 = ei;
    const int* d32 = ei + e;
    int nbkt = (n + CBN - 1) >> CBSH;  // 196

    char* w = (char*)d_ws;
    auto alloc = [&](size_t bytes) {
        char* p = w;
        w += (bytes + 255) & ~(size_t)255;
        return p;
    };
    int* rowptr = (int*)alloc(((size_t)n + 1) * 4);
    float* dinv = (float*)alloc((size_t)n * 4);
    int* csr = (int*)alloc((size_t)e * 4);
    int* H = (int*)alloc((size_t)NB2 * nbkt * 4);
    int* bstart = (int*)alloc(((size_t)nbkt + 1) * 4);
    __half* bufA = (__half*)alloc((size_t)n * 40 * 2);  // hs (max stride 40h); aliases slab
    float* bufB = (float*)alloc((size_t)n * 32 * 4);    // agg out / gemm in (fp32)
    unsigned* slab = (unsigned*)bufA;   // e*4 = 6.4MB <= 8MB

    int nb = (n + BLK - 1) / BLK;

    // CSR build: counting sort + fused build
    k_cnt<<<NB2, BLK, 0, stream>>>(d32, H, e, nbkt);
    k_bsum<<<1, BLK, 0, stream>>>(H, bstart, nbkt, e);
    k_off<<<nbkt, BLK, 0, stream>>>(H, bstart, nbkt);
    k_scatter2<<<NB2, BLK, 0, stream>>>(s32, d32, H, slab, e, nbkt);
    k_build<<<nbkt, BLK, 0, stream>>>(bstart, slab, rowptr, dinv, csr, n, e);

    // agg grids: nodes/block = 4 waves * NPN
    int ab1 = (n + 127) / 128;  // ACT=2, NPN=32
    int ab2 = (n + 83) / 84;    // ACT=3, NPN=21 (63/64 lanes active)
    int ab3 = (n + 63) / 64;    // ACT=4, NPN=16
    int ab4 = (n + 47) / 48;    // ACT=5, NPN=12 (60/64 lanes active)

    // layer 1: x[.,128] @ W1 -> hs1 fp16 (stride 16h); agg -> bufB fp32 (stride 16)
    k_gemm<128, 128, 15, 128, 16, false><<<nb, BLK, 0, stream>>>(x, W1, nullptr, dinv, bufA, n);
    k_agg<15, 16, 2, 32, 16, false><<<ab1, BLK, 0, stream>>>(rowptr, csr, bufA, bufB, dinv, nullptr, n);

    // layer 2: hs2 stride 32h; agg out stride 32  (3 lanes/node)
    k_gemm<15, 16, 20, 16, 32, true><<<nb, BLK, 0, stream>>>(bufB, W2, b1, dinv, bufA, n);
    k_agg<20, 32, 3, 21, 32, false><<<ab2, BLK, 0, stream>>>(rowptr, csr, bufA, bufB, dinv, nullptr, n);

    // layer 3  (4 lanes/node, full)
    k_gemm<20, 20, 27, 32, 32, true><<<nb, BLK, 0, stream>>>(bufB, W3, b2, dinv, bufA, n);
    k_agg<27, 32, 4, 16, 32, false><<<ab3, BLK, 0, stream>>>(rowptr, csr, bufA, bufB, dinv, nullptr, n);

    // layer 4: hs4 stride 40h (80B rows); 5 lanes/node; agg fuses final epilogue -> d_out
    k_gemm<27, 28, 36, 32, 40, true><<<nb, BLK, 0, stream>>>(bufB, W4, b3, dinv, bufA, n);
    k_agg<36, 40, 5, 12, 36, true><<<ab4, BLK, 0, stream>>>(rowptr, csr, bufA, (float*)d_out, dinv, b4, n);
}

// Round 17
// 260.508 us; speedup vs baseline: 2.0400x; 1.0423x over previous
//
#include <hip/hip_runtime.h>
#include <hip/hip_fp16.h>
#include <math.h>

#define BLK 256
#define CBSH 9           // 512 nodes per coarse bucket (196 buckets for n=100k)
#define CBN 512
#define NCBC 256
#define NB2 512

__device__ __forceinline__ float selu_f(float x) {
    const float kScale = 1.0507009873554805f;
    const float kAlpha = 1.6732632423543772f;
    return x > 0.0f ? kScale * x : kScale * kAlpha * expm1f(x);
}

__device__ __forceinline__ float2 h2f2(unsigned u) {
    __half2 h = *reinterpret_cast<__half2*>(&u);
    return __half22float2(h);
}
__device__ __forceinline__ void h8_set(float* a, uint4 v) {
    float2 f0 = h2f2(v.x), f1 = h2f2(v.y), f2 = h2f2(v.z), f3 = h2f2(v.w);
    a[0] = f0.x; a[1] = f0.y; a[2] = f1.x; a[3] = f1.y;
    a[4] = f2.x; a[5] = f2.y; a[6] = f3.x; a[7] = f3.y;
}
__device__ __forceinline__ void h8_add(float* a, uint4 v) {
    float2 f0 = h2f2(v.x), f1 = h2f2(v.y), f2 = h2f2(v.z), f3 = h2f2(v.w);
    a[0] += f0.x; a[1] += f0.y; a[2] += f1.x; a[3] += f1.y;
    a[4] += f2.x; a[5] += f2.y; a[6] += f3.x; a[7] += f3.y;
}
__device__ __forceinline__ uint4 f8_pack(const float* a) {
    __half2 h0 = __float22half2_rn(make_float2(a[0], a[1]));
    __half2 h1 = __float22half2_rn(make_float2(a[2], a[3]));
    __half2 h2 = __float22half2_rn(make_float2(a[4], a[5]));
    __half2 h3 = __float22half2_rn(make_float2(a[6], a[7]));
    uint4 u;
    u.x = *reinterpret_cast<unsigned*>(&h0);
    u.y = *reinterpret_cast<unsigned*>(&h1);
    u.z = *reinterpret_cast<unsigned*>(&h2);
    u.w = *reinterpret_cast<unsigned*>(&h3);
    return u;
}

// ---------------- CSR build (two-pass counting sort + fused build; round-16 verbatim) ----------------
__global__ void k_cnt(const int* __restrict__ dst, int* __restrict__ H, int e, int nbkt) {
    __shared__ int hist[NCBC];
    int tid = threadIdx.x;
    for (int b = tid; b < nbkt; b += BLK) hist[b] = 0;
    __syncthreads();
    int per = (e + NB2 - 1) / NB2;
    int lo = blockIdx.x * per;
    int hi = min(e, lo + per);
    for (int i = lo + tid; i < hi; i += BLK) atomicAdd(&hist[dst[i] >> CBSH], 1);
    __syncthreads();
    for (int b = tid; b < nbkt; b += BLK) H[blockIdx.x * nbkt + b] = hist[b];
}

__global__ void k_bsum(const int* __restrict__ H, int* __restrict__ bstart, int nbkt, int e) {
    __shared__ int tot[NCBC];
    int tid = threadIdx.x;
    for (int b = tid; b < nbkt; b += BLK) {
        int s = 0;
        for (int i = 0; i < NB2; ++i) s += H[i * nbkt + b];
        tot[b] = s;
    }
    __syncthreads();
    if (tid == 0) {
        int acc = 0;
        for (int b = 0; b < nbkt; ++b) {
            bstart[b] = acc;
            acc += tot[b];
        }
        bstart[nbkt] = acc;  // == e
    }
}

__global__ void k_off(int* __restrict__ H, const int* __restrict__ bstart, int nbkt) {
    __shared__ int lds[BLK];
    int b = blockIdx.x, tid = threadIdx.x;
    int v0 = H[(2 * tid) * nbkt + b];
    int v1 = H[(2 * tid + 1) * nbkt + b];
    int pair = v0 + v1;
    lds[tid] = pair;
    __syncthreads();
    int val = pair;
    for (int off = 1; off < BLK; off <<= 1) {
        int t2 = (tid >= off) ? lds[tid - off] : 0;
        __syncthreads();
        val += t2;
        lds[tid] = val;
        __syncthreads();
    }
    int excl = val - pair + bstart[b];
    H[(2 * tid) * nbkt + b] = excl;
    H[(2 * tid + 1) * nbkt + b] = excl + v0;
}

__global__ void k_scatter2(const int* __restrict__ src, const int* __restrict__ dst,
                           const int* __restrict__ H, unsigned* __restrict__ slab,
                           int e, int nbkt) {
    __shared__ int cur[NCBC];
    int tid = threadIdx.x;
    for (int b = tid; b < nbkt; b += BLK) cur[b] = H[blockIdx.x * nbkt + b];
    __syncthreads();
    int per = (e + NB2 - 1) / NB2;
    int lo = blockIdx.x * per;
    int hi = min(e, lo + per);
    for (int i = lo + tid; i < hi; i += BLK) {
        int s = src[i], d = dst[i];
        int b = d >> CBSH;
        int pos = atomicAdd(&cur[b], 1);
        slab[pos] = ((unsigned)s << CBSH) | (unsigned)(d & (CBN - 1));
    }
}

__global__ void k_build(const int* __restrict__ bstart, const unsigned* __restrict__ slab,
                        int* __restrict__ rowptr, float* __restrict__ dinv,
                        int* __restrict__ csr, int n, int e) {
    __shared__ int hist[CBN];
    __shared__ int stmp[BLK];
    int b = blockIdx.x, tid = threadIdx.x;
    hist[2 * tid] = 0;
    hist[2 * tid + 1] = 0;
    __syncthreads();
    int lo = bstart[b], hi = bstart[b + 1];
    for (int i = lo + tid; i < hi; i += BLK) atomicAdd(&hist[slab[i] & (CBN - 1)], 1);
    __syncthreads();
    int h0 = hist[2 * tid], h1 = hist[2 * tid + 1];
    int pair = h0 + h1;
    stmp[tid] = pair;
    __syncthreads();
    int val = pair;
    for (int off = 1; off < BLK; off <<= 1) {
        int t2 = (tid >= off) ? stmp[tid - off] : 0;
        __syncthreads();
        val += t2;
        stmp[tid] = val;
        __syncthreads();
    }
    int e0 = lo + val - pair;
    int e1 = e0 + h0;
    hist[2 * tid] = e0;
    hist[2 * tid + 1] = e1;
    int node0 = b << CBSH;
    int nA = node0 + 2 * tid, nB = nA + 1;
    if (nA < n) { rowptr[nA] = e0; dinv[nA] = rsqrtf((float)(h0 + 1)); }
    if (nB < n) { rowptr[nB] = e1; dinv[nB] = rsqrtf((float)(h1 + 1)); }
    if (b == 0 && tid == 0) rowptr[n] = e;
    __syncthreads();
    for (int i = lo + tid; i < hi; i += BLK) {
        unsigned p = slab[i];
        int pos = atomicAdd(&hist[p & (CBN - 1)], 1);
        csr[pos] = (int)(p >> CBSH);
    }
}

// ---------------- layer compute ----------------
// gemm1: hs1 = fp16(dinv * (x @ W1)), stride 16h (round-16 k_gemm shape, FUSE_IN=false).
__global__ void k_gemm1(const float* __restrict__ xin, const float* __restrict__ W,
                        const float* __restrict__ dinv, __half* __restrict__ hs, int n) {
    int i = blockIdx.x * BLK + threadIdx.x;
    if (i >= n) return;
    const float* xr = xin + (size_t)i * 128;
    float accf[16];
#pragma unroll
    for (int f = 0; f < 16; ++f) accf[f] = 0.0f;
#pragma unroll
    for (int k4 = 0; k4 < 32; ++k4) {
        float4 xv = *reinterpret_cast<const float4*>(xr + k4 * 4);
        float xs4[4] = {xv.x, xv.y, xv.z, xv.w};
#pragma unroll
        for (int j = 0; j < 4; ++j) {
            const int k = k4 * 4 + j;
#pragma unroll
            for (int f = 0; f < 15; ++f) accf[f] = fmaf(xs4[j], W[k * 15 + f], accf[f]);
        }
    }
    float di = dinv[i];
#pragma unroll
    for (int f = 0; f < 15; ++f) accf[f] *= di;
    accf[15] = 0.0f;
    __half2* ro2 = reinterpret_cast<__half2*>(hs + (size_t)i * 16);
#pragma unroll
    for (int f2 = 0; f2 < 8; ++f2)
        ro2[f2] = __float22half2_rn(make_float2(accf[2 * f2], accf[2 * f2 + 1]));
}

// Fused agg_l + gemm_{l+1}: gather CHI fp16 chunks/node (r16 agg body), apply input
// epilogue selu(di*sum+b), exchange K-row via LDS (wave-local, KP odd stride), then
// each lane computes output chunks c = fl, fl+CHI, ... and writes fp16 hs_out.
template <int CHI, int NPN, int SIN, int K, int KP, int FN, int CHO, int SON>
__global__ void k_aggemm(const int* __restrict__ rowptr, const int* __restrict__ csr,
                         const __half* __restrict__ hsin, const float* __restrict__ bprev,
                         const float* __restrict__ dinv, const float* __restrict__ W,
                         __half* __restrict__ hsout, int n) {
    __shared__ float xl[4][NPN][KP];
    int lane = threadIdx.x & 63;
    int wv = threadIdx.x >> 6;
    int g = lane / CHI;
    int fl = lane - g * CHI;
    int wid = (blockIdx.x * BLK + threadIdx.x) >> 6;
    int d = wid * NPN + g;
    bool active = (g < NPN) && (d < n);
    if (active) {
        int beg = rowptr[d], end = rowptr[d + 1];
        auto rowp = [&](int r) {
            return reinterpret_cast<const uint4*>(hsin + (size_t)r * SIN) + fl;
        };
        float s0[8], s1[8] = {0}, s2[8] = {0}, s3[8] = {0};
        h8_set(s0, *rowp(d));  // self
        int p = beg;
        for (; p + 8 <= end; p += 8) {
            int e0 = __builtin_nontemporal_load(csr + p);
            int e1 = __builtin_nontemporal_load(csr + p + 1);
            int e2 = __builtin_nontemporal_load(csr + p + 2);
            int e3 = __builtin_nontemporal_load(csr + p + 3);
            int e4 = __builtin_nontemporal_load(csr + p + 4);
            int e5 = __builtin_nontemporal_load(csr + p + 5);
            int e6 = __builtin_nontemporal_load(csr + p + 6);
            int e7 = __builtin_nontemporal_load(csr + p + 7);
            uint4 v0 = *rowp(e0), v1 = *rowp(e1), v2 = *rowp(e2), v3 = *rowp(e3);
            uint4 v4 = *rowp(e4), v5 = *rowp(e5), v6 = *rowp(e6), v7 = *rowp(e7);
            h8_add(s0, v0); h8_add(s1, v1); h8_add(s2, v2); h8_add(s3, v3);
            h8_add(s0, v4); h8_add(s1, v5); h8_add(s2, v6); h8_add(s3, v7);
        }
        for (; p + 4 <= end; p += 4) {
            int e0 = __builtin_nontemporal_load(csr + p);
            int e1 = __builtin_nontemporal_load(csr + p + 1);
            int e2 = __builtin_nontemporal_load(csr + p + 2);
            int e3 = __builtin_nontemporal_load(csr + p + 3);
            uint4 v0 = *rowp(e0), v1 = *rowp(e1), v2 = *rowp(e2), v3 = *rowp(e3);
            h8_add(s0, v0); h8_add(s1, v1); h8_add(s2, v2); h8_add(s3, v3);
        }
        for (; p < end; ++p) h8_add(s0, *rowp(__builtin_nontemporal_load(csr + p)));
        float di = dinv[d];
#pragma unroll
        for (int j = 0; j < 8; ++j) {
            int k = fl * 8 + j;
            if (k < K) {
                float s = (s0[j] + s1[j]) + (s2[j] + s3[j]);
                xl[wv][g][k] = selu_f(di * s + bprev[k]);  // input epilogue (as old gemm)
            }
        }
    }
    __syncthreads();
    if (active) {
        float di = dinv[d];
#pragma unroll
        for (int c = fl; c < CHO; c += CHI) {
            float acc[8];
#pragma unroll
            for (int j = 0; j < 8; ++j) acc[j] = 0.0f;
#pragma unroll
            for (int k = 0; k < K; ++k) {
                float xv = xl[wv][g][k];
#pragma unroll
                for (int j = 0; j < 8; ++j) {
                    int col = c * 8 + j;
                    if (col < FN) acc[j] = fmaf(xv, W[k * FN + col], acc[j]);
                }
            }
            float gg[8];
#pragma unroll
            for (int j = 0; j < 8; ++j) {
                int col = c * 8 + j;
                gg[j] = (col < FN) ? di * acc[j] : 0.0f;
            }
            *reinterpret_cast<uint4*>(hsout + (size_t)d * SON + c * 8) = f8_pack(gg);
        }
    }
}

// Final CSR gather (round-16 verbatim, ACT=5/NPN=12, fused final epilogue).
template <int F, int S, int ACT, int NPN>
__global__ void k_aggL(const int* __restrict__ rowptr, const int* __restrict__ csr,
                       const __half* __restrict__ hs, float* __restrict__ out,
                       const float* __restrict__ dinv, const float* __restrict__ bias,
                       int n) {
    int lane = threadIdx.x & 63;
    int g = lane / ACT;
    int fl = lane - g * ACT;
    int wid = (blockIdx.x * BLK + threadIdx.x) >> 6;
    int d = wid * NPN + g;
    if (g >= NPN || d >= n) return;
    int beg = rowptr[d], end = rowptr[d + 1];
    auto rowp = [&](int r) {
        return reinterpret_cast<const uint4*>(hs + (size_t)r * S) + fl;
    };
    float s0[8], s1[8] = {0}, s2[8] = {0}, s3[8] = {0};
    h8_set(s0, *rowp(d));  // self
    int p = beg;
    for (; p + 8 <= end; p += 8) {
        int e0 = __builtin_nontemporal_load(csr + p);
        int e1 = __builtin_nontemporal_load(csr + p + 1);
        int e2 = __builtin_nontemporal_load(csr + p + 2);
        int e3 = __builtin_nontemporal_load(csr + p + 3);
        int e4 = __builtin_nontemporal_load(csr + p + 4);
        int e5 = __builtin_nontemporal_load(csr + p + 5);
        int e6 = __builtin_nontemporal_load(csr + p + 6);
        int e7 = __builtin_nontemporal_load(csr + p + 7);
        uint4 v0 = *rowp(e0), v1 = *rowp(e1), v2 = *rowp(e2), v3 = *rowp(e3);
        uint4 v4 = *rowp(e4), v5 = *rowp(e5), v6 = *rowp(e6), v7 = *rowp(e7);
        h8_add(s0, v0); h8_add(s1, v1); h8_add(s2, v2); h8_add(s3, v3);
        h8_add(s0, v4); h8_add(s1, v5); h8_add(s2, v6); h8_add(s3, v7);
    }
    for (; p + 4 <= end; p += 4) {
        int e0 = __builtin_nontemporal_load(csr + p);
        int e1 = __builtin_nontemporal_load(csr + p + 1);
        int e2 = __builtin_nontemporal_load(csr + p + 2);
        int e3 = __builtin_nontemporal_load(csr + p + 3);
        uint4 v0 = *rowp(e0), v1 = *rowp(e1), v2 = *rowp(e2), v3 = *rowp(e3);
        h8_add(s0, v0); h8_add(s1, v1); h8_add(s2, v2); h8_add(s3, v3);
    }
    for (; p < end; ++p) h8_add(s0, *rowp(__builtin_nontemporal_load(csr + p)));
    float dv = dinv[d];
    float r[8];
#pragma unroll
    for (int j = 0; j < 8; ++j) {
        int col = fl * 8 + j;
        float s = (s0[j] + s1[j]) + (s2[j] + s3[j]);
        r[j] = (col < F) ? selu_f(dv * s + bias[col]) : 0.0f;
    }
    float* op = out + (size_t)d * F + fl * 8;
    *reinterpret_cast<float4*>(op) = make_float4(r[0], r[1], r[2], r[3]);
    if (fl * 8 + 4 < F)
        *reinterpret_cast<float4*>(op + 4) = make_float4(r[4], r[5], r[6], r[7]);
}

extern "C" void kernel_launch(void* const* d_in, const int* in_sizes, int n_in,
                              void* d_out, int out_size, void* d_ws, size_t ws_size,
                              hipStream_t stream) {
    const float* x = (const float*)d_in[0];
    const int* ei = (const int*)d_in[1];  // int32 on device
    const float* W1 = (const float*)d_in[2];
    const float* b1 = (const float*)d_in[3];
    const float* W2 = (const float*)d_in[4];
    const float* b2 = (const float*)d_in[5];
    const float* W3 = (const float*)d_in[6];
    const float* b3 = (const float*)d_in[7];
    const float* W4 = (const float*)d_in[8];
    const float* b4 = (const float*)d_in[9];

    int n = in_sizes[0] / 128;
    int e = in_sizes[1] / 2;
    const int* s32 = ei;
    const int* d32 = ei + e;
    int nbkt = (n + CBN - 1) >> CBSH;  // 196

    char* w = (char*)d_ws;
    auto alloc = [&](size_t bytes) {
        char* p = w;
        w += (bytes + 255) & ~(size_t)255;
        return p;
    };
    int* rowptr = (int*)alloc(((size_t)n + 1) * 4);
    float* dinv = (float*)alloc((size_t)n * 4);
    int* csr = (int*)alloc((size_t)e * 4);
    int* H = (int*)alloc((size_t)NB2 * nbkt * 4);
    int* bstart = (int*)alloc(((size_t)nbkt + 1) * 4);
    __half* bufA = (__half*)alloc((size_t)n * 40 * 2);  // hs1/hs3; aliases slab
    __half* bufC = (__half*)alloc((size_t)n * 40 * 2);  // hs2/hs4
    unsigned* slab = (unsigned*)bufA;   // e*4 = 6.4MB <= 8MB

    int nb = (n + BLK - 1) / BLK;

    // CSR build: counting sort + fused build
    k_cnt<<<NB2, BLK, 0, stream>>>(d32, H, e, nbkt);
    k_bsum<<<1, BLK, 0, stream>>>(H, bstart, nbkt, e);
    k_off<<<nbkt, BLK, 0, stream>>>(H, bstart, nbkt);
    k_scatter2<<<NB2, BLK, 0, stream>>>(s32, d32, H, slab, e, nbkt);
    k_build<<<nbkt, BLK, 0, stream>>>(bstart, slab, rowptr, dinv, csr, n, e);

    // grids: nodes/block = 4 waves * NPN
    int ab1 = (n + 127) / 128;  // CHI=2, NPN=32
    int ab2 = (n + 83) / 84;    // CHI=3, NPN=21
    int ab3 = (n + 63) / 64;    // CHI=4, NPN=16
    int ab4 = (n + 47) / 48;    // ACT=5, NPN=12

    // layer 1 gemm: x @ W1 -> hs1 (bufA, stride 16h)
    k_gemm1<<<nb, BLK, 0, stream>>>(x, W1, dinv, bufA, n);

    // fused agg1+gemm2: gather hs1 -> selu epilogue -> @W2 -> hs2 (bufC, stride 32h)
    k_aggemm<2, 32, 16, 15, 17, 20, 3, 32><<<ab1, BLK, 0, stream>>>(
        rowptr, csr, bufA, b1, dinv, W2, bufC, n);

    // fused agg2+gemm3: gather hs2 -> @W3 -> hs3 (bufA, stride 32h)
    k_aggemm<3, 21, 32, 20, 21, 27, 4, 32><<<ab2, BLK, 0, stream>>>(
        rowptr, csr, bufC, b2, dinv, W3, bufA, n);

    // fused agg3+gemm4: gather hs3 -> @W4 -> hs4 (bufC, stride 40h)
    k_aggemm<4, 16, 32, 27, 29, 36, 5, 40><<<ab3, BLK, 0, stream>>>(
        rowptr, csr, bufA, b3, dinv, W4, bufC, n);

    // final agg: gather hs4, fused selu/bias epilogue -> d_out
    k_aggL<36, 40, 5, 12><<<ab4, BLK, 0, stream>>>(rowptr, csr, bufC, (float*)d_out, dinv, b4, n);
}

// Round 18
// 249.409 us; speedup vs baseline: 2.1307x; 1.0445x over previous
//
#include <hip/hip_runtime.h>
#include <hip/hip_fp16.h>
#include <math.h>

#define BLK 256
#define CBSH 9           // 512 nodes per coarse bucket (196 buckets for n=100k)
#define CBN 512
#define NCBC 256
#define NB2 512

__device__ __forceinline__ float selu_f(float x) {
    const float kScale = 1.0507009873554805f;
    const float kAlpha = 1.6732632423543772f;
    return x > 0.0f ? kScale * x : kScale * kAlpha * expm1f(x);
}

__device__ __forceinline__ float2 h2f2(unsigned u) {
    __half2 h = *reinterpret_cast<__half2*>(&u);
    return __half22float2(h);
}
__device__ __forceinline__ void h8_set(float* a, uint4 v) {
    float2 f0 = h2f2(v.x), f1 = h2f2(v.y), f2 = h2f2(v.z), f3 = h2f2(v.w);
    a[0] = f0.x; a[1] = f0.y; a[2] = f1.x; a[3] = f1.y;
    a[4] = f2.x; a[5] = f2.y; a[6] = f3.x; a[7] = f3.y;
}
__device__ __forceinline__ void h8_add(float* a, uint4 v) {
    float2 f0 = h2f2(v.x), f1 = h2f2(v.y), f2 = h2f2(v.z), f3 = h2f2(v.w);
    a[0] += f0.x; a[1] += f0.y; a[2] += f1.x; a[3] += f1.y;
    a[4] += f2.x; a[5] += f2.y; a[6] += f3.x; a[7] += f3.y;
}
__device__ __forceinline__ uint4 f8_pack(const float* a) {
    __half2 h0 = __float22half2_rn(make_float2(a[0], a[1]));
    __half2 h1 = __float22half2_rn(make_float2(a[2], a[3]));
    __half2 h2 = __float22half2_rn(make_float2(a[4], a[5]));
    __half2 h3 = __float22half2_rn(make_float2(a[6], a[7]));
    uint4 u;
    u.x = *reinterpret_cast<unsigned*>(&h0);
    u.y = *reinterpret_cast<unsigned*>(&h1);
    u.z = *reinterpret_cast<unsigned*>(&h2);
    u.w = *reinterpret_cast<unsigned*>(&h3);
    return u;
}

// ---------------- CSR build (two-pass counting sort + fused build; round-16 verbatim) ----------------
__global__ void k_cnt(const int* __restrict__ dst, int* __restrict__ H, int e, int nbkt) {
    __shared__ int hist[NCBC];
    int tid = threadIdx.x;
    for (int b = tid; b < nbkt; b += BLK) hist[b] = 0;
    __syncthreads();
    int per = (e + NB2 - 1) / NB2;
    int lo = blockIdx.x * per;
    int hi = min(e, lo + per);
    for (int i = lo + tid; i < hi; i += BLK) atomicAdd(&hist[dst[i] >> CBSH], 1);
    __syncthreads();
    for (int b = tid; b < nbkt; b += BLK) H[blockIdx.x * nbkt + b] = hist[b];
}

__global__ void k_bsum(const int* __restrict__ H, int* __restrict__ bstart, int nbkt, int e) {
    __shared__ int tot[NCBC];
    int tid = threadIdx.x;
    for (int b = tid; b < nbkt; b += BLK) {
        int s = 0;
        for (int i = 0; i < NB2; ++i) s += H[i * nbkt + b];
        tot[b] = s;
    }
    __syncthreads();
    if (tid == 0) {
        int acc = 0;
        for (int b = 0; b < nbkt; ++b) {
            bstart[b] = acc;
            acc += tot[b];
        }
        bstart[nbkt] = acc;  // == e
    }
}

__global__ void k_off(int* __restrict__ H, const int* __restrict__ bstart, int nbkt) {
    __shared__ int lds[BLK];
    int b = blockIdx.x, tid = threadIdx.x;
    int v0 = H[(2 * tid) * nbkt + b];
    int v1 = H[(2 * tid + 1) * nbkt + b];
    int pair = v0 + v1;
    lds[tid] = pair;
    __syncthreads();
    int val = pair;
    for (int off = 1; off < BLK; off <<= 1) {
        int t2 = (tid >= off) ? lds[tid - off] : 0;
        __syncthreads();
        val += t2;
        lds[tid] = val;
        __syncthreads();
    }
    int excl = val - pair + bstart[b];
    H[(2 * tid) * nbkt + b] = excl;
    H[(2 * tid + 1) * nbkt + b] = excl + v0;
}

__global__ void k_scatter2(const int* __restrict__ src, const int* __restrict__ dst,
                           const int* __restrict__ H, unsigned* __restrict__ slab,
                           int e, int nbkt) {
    __shared__ int cur[NCBC];
    int tid = threadIdx.x;
    for (int b = tid; b < nbkt; b += BLK) cur[b] = H[blockIdx.x * nbkt + b];
    __syncthreads();
    int per = (e + NB2 - 1) / NB2;
    int lo = blockIdx.x * per;
    int hi = min(e, lo + per);
    for (int i = lo + tid; i < hi; i += BLK) {
        int s = src[i], d = dst[i];
        int b = d >> CBSH;
        int pos = atomicAdd(&cur[b], 1);
        slab[pos] = ((unsigned)s << CBSH) | (unsigned)(d & (CBN - 1));
    }
}

__global__ void k_build(const int* __restrict__ bstart, const unsigned* __restrict__ slab,
                        int* __restrict__ rowptr, float* __restrict__ dinv,
                        int* __restrict__ csr, int n, int e) {
    __shared__ int hist[CBN];
    __shared__ int stmp[BLK];
    int b = blockIdx.x, tid = threadIdx.x;
    hist[2 * tid] = 0;
    hist[2 * tid + 1] = 0;
    __syncthreads();
    int lo = bstart[b], hi = bstart[b + 1];
    for (int i = lo + tid; i < hi; i += BLK) atomicAdd(&hist[slab[i] & (CBN - 1)], 1);
    __syncthreads();
    int h0 = hist[2 * tid], h1 = hist[2 * tid + 1];
    int pair = h0 + h1;
    stmp[tid] = pair;
    __syncthreads();
    int val = pair;
    for (int off = 1; off < BLK; off <<= 1) {
        int t2 = (tid >= off) ? stmp[tid - off] : 0;
        __syncthreads();
        val += t2;
        stmp[tid] = val;
        __syncthreads();
    }
    int e0 = lo + val - pair;
    int e1 = e0 + h0;
    hist[2 * tid] = e0;
    hist[2 * tid + 1] = e1;
    int node0 = b << CBSH;
    int nA = node0 + 2 * tid, nB = nA + 1;
    if (nA < n) { rowptr[nA] = e0; dinv[nA] = rsqrtf((float)(h0 + 1)); }
    if (nB < n) { rowptr[nB] = e1; dinv[nB] = rsqrtf((float)(h1 + 1)); }
    if (b == 0 && tid == 0) rowptr[n] = e;
    __syncthreads();
    for (int i = lo + tid; i < hi; i += BLK) {
        unsigned p = slab[i];
        int pos = atomicAdd(&hist[p & (CBN - 1)], 1);
        csr[pos] = (int)(p >> CBSH);
    }
}

// ---------------- layer compute ----------------
// gemm1: hs1 = fp16(dinv * (x @ W1)), stride 16h.
__global__ void k_gemm1(const float* __restrict__ xin, const float* __restrict__ W,
                        const float* __restrict__ dinv, __half* __restrict__ hs, int n) {
    int i = blockIdx.x * BLK + threadIdx.x;
    if (i >= n) return;
    const float* xr = xin + (size_t)i * 128;
    float accf[16];
#pragma unroll
    for (int f = 0; f < 16; ++f) accf[f] = 0.0f;
#pragma unroll
    for (int k4 = 0; k4 < 32; ++k4) {
        float4 xv = *reinterpret_cast<const float4*>(xr + k4 * 4);
        float xs4[4] = {xv.x, xv.y, xv.z, xv.w};
#pragma unroll
        for (int j = 0; j < 4; ++j) {
            const int k = k4 * 4 + j;
#pragma unroll
            for (int f = 0; f < 15; ++f) accf[f] = fmaf(xs4[j], W[k * 15 + f], accf[f]);
        }
    }
    float di = dinv[i];
#pragma unroll
    for (int f = 0; f < 15; ++f) accf[f] *= di;
    accf[15] = 0.0f;
    __half2* ro2 = reinterpret_cast<__half2*>(hs + (size_t)i * 16);
#pragma unroll
    for (int f2 = 0; f2 < 8; ++f2)
        ro2[f2] = __float22half2_rn(make_float2(accf[2 * f2], accf[2 * f2 + 1]));
}

// Fused agg_l + gemm_{l+1}: gather CHI fp16 chunks/node, input epilogue selu(di*sum+b),
// wave-register exchange via __shfl (no LDS, no barrier), then each lane computes
// output chunks c = fl, fl+CHI, ... and writes fp16 hs_out.
template <int CHI, int NPN, int SIN, int K, int FN, int CHO, int SON>
__global__ void k_aggemm(const int* __restrict__ rowptr, const int* __restrict__ csr,
                         const __half* __restrict__ hsin, const float* __restrict__ bprev,
                         const float* __restrict__ dinv, const float* __restrict__ W,
                         __half* __restrict__ hsout, int n) {
    int lane = threadIdx.x & 63;
    int g = lane / CHI;
    int fl = lane - g * CHI;
    int wid = (blockIdx.x * BLK + threadIdx.x) >> 6;
    int d = wid * NPN + g;
    bool active = (g < NPN) && (d < n);
    float xv8[8];
#pragma unroll
    for (int j = 0; j < 8; ++j) xv8[j] = 0.0f;
    float di = 0.0f;
    if (active) {
        di = dinv[d];
        int beg = rowptr[d], end = rowptr[d + 1];
        auto rowp = [&](int r) {
            return reinterpret_cast<const uint4*>(hsin + (size_t)r * SIN) + fl;
        };
        float s0[8], s1[8] = {0}, s2[8] = {0}, s3[8] = {0};
        h8_set(s0, *rowp(d));  // self
        int p = beg;
        for (; p + 8 <= end; p += 8) {
            int e0 = __builtin_nontemporal_load(csr + p);
            int e1 = __builtin_nontemporal_load(csr + p + 1);
            int e2 = __builtin_nontemporal_load(csr + p + 2);
            int e3 = __builtin_nontemporal_load(csr + p + 3);
            int e4 = __builtin_nontemporal_load(csr + p + 4);
            int e5 = __builtin_nontemporal_load(csr + p + 5);
            int e6 = __builtin_nontemporal_load(csr + p + 6);
            int e7 = __builtin_nontemporal_load(csr + p + 7);
            uint4 v0 = *rowp(e0), v1 = *rowp(e1), v2 = *rowp(e2), v3 = *rowp(e3);
            uint4 v4 = *rowp(e4), v5 = *rowp(e5), v6 = *rowp(e6), v7 = *rowp(e7);
            h8_add(s0, v0); h8_add(s1, v1); h8_add(s2, v2); h8_add(s3, v3);
            h8_add(s0, v4); h8_add(s1, v5); h8_add(s2, v6); h8_add(s3, v7);
        }
        for (; p + 4 <= end; p += 4) {
            int e0 = __builtin_nontemporal_load(csr + p);
            int e1 = __builtin_nontemporal_load(csr + p + 1);
            int e2 = __builtin_nontemporal_load(csr + p + 2);
            int e3 = __builtin_nontemporal_load(csr + p + 3);
            uint4 v0 = *rowp(e0), v1 = *rowp(e1), v2 = *rowp(e2), v3 = *rowp(e3);
            h8_add(s0, v0); h8_add(s1, v1); h8_add(s2, v2); h8_add(s3, v3);
        }
        for (; p < end; ++p) h8_add(s0, *rowp(__builtin_nontemporal_load(csr + p)));
#pragma unroll
        for (int j = 0; j < 8; ++j) {
            int k = fl * 8 + j;
            if (k < K) {
                float s = (s0[j] + s1[j]) + (s2[j] + s3[j]);
                xv8[j] = selu_f(di * s + bprev[k]);  // input epilogue (as old gemm)
            }
        }
    }
    // Wave-register exchange: all lanes converged; xk[k] = group g's K-row.
    int base = lane - fl;  // = g * CHI
    float xk[K];
#pragma unroll
    for (int k = 0; k < K; ++k)
        xk[k] = __shfl(xv8[k & 7], (base + (k >> 3)) & 63, 64);
    if (active) {
#pragma unroll
        for (int m = 0; m < (CHO + CHI - 1) / CHI; ++m) {
            int c = fl + m * CHI;
            if (c < CHO) {
                float acc[8];
#pragma unroll
                for (int j = 0; j < 8; ++j) acc[j] = 0.0f;
#pragma unroll
                for (int k = 0; k < K; ++k) {
#pragma unroll
                    for (int j = 0; j < 8; ++j) {
                        int col = c * 8 + j;
                        if (col < FN) acc[j] = fmaf(xk[k], W[k * FN + col], acc[j]);
                    }
                }
                float gg[8];
#pragma unroll
                for (int j = 0; j < 8; ++j) {
                    int col = c * 8 + j;
                    gg[j] = (col < FN) ? di * acc[j] : 0.0f;
                }
                *reinterpret_cast<uint4*>(hsout + (size_t)d * SON + c * 8) = f8_pack(gg);
            }
        }
    }
}

// Final CSR gather (round-16 verbatim, ACT=5/NPN=12, fused final epilogue).
template <int F, int S, int ACT, int NPN>
__global__ void k_aggL(const int* __restrict__ rowptr, const int* __restrict__ csr,
                       const __half* __restrict__ hs, float* __restrict__ out,
                       const float* __restrict__ dinv, const float* __restrict__ bias,
                       int n) {
    int lane = threadIdx.x & 63;
    int g = lane / ACT;
    int fl = lane - g * ACT;
    int wid = (blockIdx.x * BLK + threadIdx.x) >> 6;
    int d = wid * NPN + g;
    if (g >= NPN || d >= n) return;
    int beg = rowptr[d], end = rowptr[d + 1];
    auto rowp = [&](int r) {
        return reinterpret_cast<const uint4*>(hs + (size_t)r * S) + fl;
    };
    float s0[8], s1[8] = {0}, s2[8] = {0}, s3[8] = {0};
    h8_set(s0, *rowp(d));  // self
    int p = beg;
    for (; p + 8 <= end; p += 8) {
        int e0 = __builtin_nontemporal_load(csr + p);
        int e1 = __builtin_nontemporal_load(csr + p + 1);
        int e2 = __builtin_nontemporal_load(csr + p + 2);
        int e3 = __builtin_nontemporal_load(csr + p + 3);
        int e4 = __builtin_nontemporal_load(csr + p + 4);
        int e5 = __builtin_nontemporal_load(csr + p + 5);
        int e6 = __builtin_nontemporal_load(csr + p + 6);
        int e7 = __builtin_nontemporal_load(csr + p + 7);
        uint4 v0 = *rowp(e0), v1 = *rowp(e1), v2 = *rowp(e2), v3 = *rowp(e3);
        uint4 v4 = *rowp(e4), v5 = *rowp(e5), v6 = *rowp(e6), v7 = *rowp(e7);
        h8_add(s0, v0); h8_add(s1, v1); h8_add(s2, v2); h8_add(s3, v3);
        h8_add(s0, v4); h8_add(s1, v5); h8_add(s2, v6); h8_add(s3, v7);
    }
    for (; p + 4 <= end; p += 4) {
        int e0 = __builtin_nontemporal_load(csr + p);
        int e1 = __builtin_nontemporal_load(csr + p + 1);
        int e2 = __builtin_nontemporal_load(csr + p + 2);
        int e3 = __builtin_nontemporal_load(csr + p + 3);
        uint4 v0 = *rowp(e0), v1 = *rowp(e1), v2 = *rowp(e2), v3 = *rowp(e3);
        h8_add(s0, v0); h8_add(s1, v1); h8_add(s2, v2); h8_add(s3, v3);
    }
    for (; p < end; ++p) h8_add(s0, *rowp(__builtin_nontemporal_load(csr + p)));
    float dv = dinv[d];
    float r[8];
#pragma unroll
    for (int j = 0; j < 8; ++j) {
        int col = fl * 8 + j;
        float s = (s0[j] + s1[j]) + (s2[j] + s3[j]);
        r[j] = (col < F) ? selu_f(dv * s + bias[col]) : 0.0f;
    }
    float* op = out + (size_t)d * F + fl * 8;
    *reinterpret_cast<float4*>(op) = make_float4(r[0], r[1], r[2], r[3]);
    if (fl * 8 + 4 < F)
        *reinterpret_cast<float4*>(op + 4) = make_float4(r[4], r[5], r[6], r[7]);
}

extern "C" void kernel_launch(void* const* d_in, const int* in_sizes, int n_in,
                              void* d_out, int out_size, void* d_ws, size_t ws_size,
                              hipStream_t stream) {
    const float* x = (const float*)d_in[0];
    const int* ei = (const int*)d_in[1];  // int32 on device
    const float* W1 = (const float*)d_in[2];
    const float* b1 = (const float*)d_in[3];
    const float* W2 = (const float*)d_in[4];
    const float* b2 = (const float*)d_in[5];
    const float* W3 = (const float*)d_in[6];
    const float* b3 = (const float*)d_in[7];
    const float* W4 = (const float*)d_in[8];
    const float* b4 = (const float*)d_in[9];

    int n = in_sizes[0] / 128;
    int e = in_sizes[1] / 2;
    const int* s32 = ei;
    const int* d32 = ei + e;
    int nbkt = (n + CBN - 1) >> CBSH;  // 196

    char* w = (char*)d_ws;
    auto alloc = [&](size_t bytes) {
        char* p = w;
        w += (bytes + 255) & ~(size_t)255;
        return p;
    };
    int* rowptr = (int*)alloc(((size_t)n + 1) * 4);
    float* dinv = (float*)alloc((size_t)n * 4);
    int* csr = (int*)alloc((size_t)e * 4);
    int* H = (int*)alloc((size_t)NB2 * nbkt * 4);
    int* bstart = (int*)alloc(((size_t)nbkt + 1) * 4);
    __half* bufA = (__half*)alloc((size_t)n * 40 * 2);  // hs1/hs3; aliases slab
    __half* bufC = (__half*)alloc((size_t)n * 40 * 2);  // hs2/hs4
    unsigned* slab = (unsigned*)bufA;   // e*4 = 6.4MB <= 8MB

    int nb = (n + BLK - 1) / BLK;

    // CSR build: counting sort + fused build
    k_cnt<<<NB2, BLK, 0, stream>>>(d32, H, e, nbkt);
    k_bsum<<<1, BLK, 0, stream>>>(H, bstart, nbkt, e);
    k_off<<<nbkt, BLK, 0, stream>>>(H, bstart, nbkt);
    k_scatter2<<<NB2, BLK, 0, stream>>>(s32, d32, H, slab, e, nbkt);
    k_build<<<nbkt, BLK, 0, stream>>>(bstart, slab, rowptr, dinv, csr, n, e);

    // grids: nodes/block = 4 waves * NPN
    int ab1 = (n + 127) / 128;  // CHI=2, NPN=32
    int ab2 = (n + 83) / 84;    // CHI=3, NPN=21
    int ab3 = (n + 63) / 64;    // CHI=4, NPN=16
    int ab4 = (n + 47) / 48;    // ACT=5, NPN=12

    // layer 1 gemm: x @ W1 -> hs1 (bufA, stride 16h)
    k_gemm1<<<nb, BLK, 0, stream>>>(x, W1, dinv, bufA, n);

    // fused agg1+gemm2: gather hs1 -> selu epilogue -> @W2 -> hs2 (bufC, stride 32h)
    k_aggemm<2, 32, 16, 15, 20, 3, 32><<<ab1, BLK, 0, stream>>>(
        rowptr, csr, bufA, b1, dinv, W2, bufC, n);

    // fused agg2+gemm3: gather hs2 -> @W3 -> hs3 (bufA, stride 32h)
    k_aggemm<3, 21, 32, 20, 27, 4, 32><<<ab2, BLK, 0, stream>>>(
        rowptr, csr, bufC, b2, dinv, W3, bufA, n);

    // fused agg3+gemm4: gather hs3 -> @W4 -> hs4 (bufC, stride 40h)
    k_aggemm<4, 16, 32, 27, 36, 5, 40><<<ab3, BLK, 0, stream>>>(
        rowptr, csr, bufA, b3, dinv, W4, bufC, n);

    // final agg: gather hs4, fused selu/bias epilogue -> d_out
    k_aggL<36, 40, 5, 12><<<ab4, BLK, 0, stream>>>(rowptr, csr, bufC, (float*)d_out, dinv, b4, n);
}